// Round 2
// baseline (2520.336 us; speedup 1.0000x reference)
//
#include <hip/hip_runtime.h>
#include <hip/hip_bf16.h>
#include <cstddef>

#define N_EMBD 512
#define NHEADS 8
#define HEADD  64
#define TBLK   256
#define BATCH  64
#define FF_DIM 2048
#define MROWS  (BATCH * TBLK)   // 16384

// ---------------------------------------------------------------------------
// LayerNorm: one wave (64 lanes) per row of 512 floats. 4 waves per block.
// ---------------------------------------------------------------------------
__global__ __launch_bounds__(256) void ln_kernel(
    const float* __restrict__ in, float* __restrict__ out,
    const float* __restrict__ g, const float* __restrict__ b)
{
    int row  = blockIdx.x * 4 + (threadIdx.x >> 6);
    int lane = threadIdx.x & 63;
    const float4* r = (const float4*)(in + (size_t)row * N_EMBD);
    float4 v0 = r[lane];
    float4 v1 = r[lane + 64];
    float s  = (v0.x + v0.y) + (v0.z + v0.w) + (v1.x + v1.y) + (v1.z + v1.w);
    float ss = v0.x*v0.x + v0.y*v0.y + v0.z*v0.z + v0.w*v0.w
             + v1.x*v1.x + v1.y*v1.y + v1.z*v1.z + v1.w*v1.w;
    #pragma unroll
    for (int off = 32; off; off >>= 1) {
        s  += __shfl_xor(s, off);
        ss += __shfl_xor(ss, off);
    }
    float mu  = s * (1.0f / 512.0f);
    float var = ss * (1.0f / 512.0f) - mu * mu;
    float rs  = rsqrtf(var + 1e-5f);
    const float4* g4 = (const float4*)g;
    const float4* b4 = (const float4*)b;
    float4 G0 = g4[lane], G1 = g4[lane + 64];
    float4 B0 = b4[lane], B1 = b4[lane + 64];
    float4 o0, o1;
    o0.x = (v0.x - mu) * rs * G0.x + B0.x;
    o0.y = (v0.y - mu) * rs * G0.y + B0.y;
    o0.z = (v0.z - mu) * rs * G0.z + B0.z;
    o0.w = (v0.w - mu) * rs * G0.w + B0.w;
    o1.x = (v1.x - mu) * rs * G1.x + B1.x;
    o1.y = (v1.y - mu) * rs * G1.y + B1.y;
    o1.z = (v1.z - mu) * rs * G1.z + B1.z;
    o1.w = (v1.w - mu) * rs * G1.w + B1.w;
    float4* o = (float4*)(out + (size_t)row * N_EMBD);
    o[lane]      = o0;
    o[lane + 64] = o1;
}

// ---------------------------------------------------------------------------
// fp32 tiled GEMM: C[M,N] = A[M,K] @ W[K,N] (+bias) (+relu) (+resid)
// A row stride = K; W row stride = ldW; C/resid row stride = ldC.
// 64x64 tile, BK=16, 256 threads, 4x4 acc per thread.
// ---------------------------------------------------------------------------
__global__ __launch_bounds__(256) void gemm64(
    const float* __restrict__ A, const float* __restrict__ W,
    const float* __restrict__ bias, const float* __restrict__ resid,
    float* __restrict__ C, int M, int N, int K, int ldW, int ldC, int relu)
{
    __shared__ float As[16][64];
    __shared__ float Bs[16][64];
    const int tid  = threadIdx.x;
    const int tx   = tid & 15;       // col group
    const int ty   = tid >> 4;       // row group
    const int row0 = blockIdx.y * 64;
    const int col0 = blockIdx.x * 64;
    const int arow = tid >> 2;            // 0..63
    const int akc  = (tid & 3) * 4;       // 0,4,8,12
    const int brow = tid >> 4;            // 0..15
    const int bcol = (tid & 15) * 4;      // 0..60

    float acc[4][4] = {};
    const float* Aptr = A + (size_t)(row0 + arow) * K + akc;
    const float* Wptr = W + (size_t)brow * ldW + col0 + bcol;

    for (int k0 = 0; k0 < K; k0 += 16) {
        float4 a = *(const float4*)(Aptr + k0);
        float4 b = *(const float4*)(Wptr + (size_t)k0 * ldW);
        __syncthreads();
        As[akc + 0][arow] = a.x;
        As[akc + 1][arow] = a.y;
        As[akc + 2][arow] = a.z;
        As[akc + 3][arow] = a.w;
        *(float4*)&Bs[brow][bcol] = b;
        __syncthreads();
        #pragma unroll
        for (int kk = 0; kk < 16; ++kk) {
            float4 av = *(const float4*)&As[kk][ty * 4];
            float4 bv = *(const float4*)&Bs[kk][tx * 4];
            float a0[4] = {av.x, av.y, av.z, av.w};
            float b0[4] = {bv.x, bv.y, bv.z, bv.w};
            #pragma unroll
            for (int i = 0; i < 4; ++i)
                #pragma unroll
                for (int j = 0; j < 4; ++j)
                    acc[i][j] = fmaf(a0[i], b0[j], acc[i][j]);
        }
    }

    float bvals[4] = {0.f, 0.f, 0.f, 0.f};
    if (bias) {
        float4 b4 = *(const float4*)&bias[col0 + tx * 4];
        bvals[0] = b4.x; bvals[1] = b4.y; bvals[2] = b4.z; bvals[3] = b4.w;
    }
    #pragma unroll
    for (int i = 0; i < 4; ++i) {
        int r = row0 + ty * 4 + i;
        float4 o;
        o.x = acc[i][0] + bvals[0];
        o.y = acc[i][1] + bvals[1];
        o.z = acc[i][2] + bvals[2];
        o.w = acc[i][3] + bvals[3];
        if (relu) {
            o.x = fmaxf(o.x, 0.f); o.y = fmaxf(o.y, 0.f);
            o.z = fmaxf(o.z, 0.f); o.w = fmaxf(o.w, 0.f);
        }
        if (resid) {
            float4 rv = *(const float4*)&resid[(size_t)r * ldC + col0 + tx * 4];
            o.x += rv.x; o.y += rv.y; o.z += rv.z; o.w += rv.w;
        }
        *(float4*)&C[(size_t)r * ldC + col0 + tx * 4] = o;
    }
}

// ---------------------------------------------------------------------------
// Attention: one block per (batch, head); one thread per query row.
// Online softmax over 16-key LDS tiles. Matches reference -1e9 masking.
// ---------------------------------------------------------------------------
template<int CAUSAL>
__global__ __launch_bounds__(256) void attn_kernel(
    const float* __restrict__ Q, const float* __restrict__ Km,
    const float* __restrict__ Vm, const int* __restrict__ mask,
    float* __restrict__ O)
{
    __shared__ float Ks[16][64];
    __shared__ float Vs[16][64];
    const int bh   = blockIdx.x;
    const int b    = bh >> 3;
    const int h    = bh & 7;
    const int qrow = threadIdx.x;
    const float scale = 0.04419417382415922f;   // 512^-0.5

    const float* qp = Q + ((size_t)(b * TBLK + qrow)) * N_EMBD + h * HEADD;
    float4 q[16];
    #pragma unroll
    for (int j = 0; j < 16; ++j) q[j] = ((const float4*)qp)[j];

    float4 acc[16];
    #pragma unroll
    for (int j = 0; j < 16; ++j) acc[j] = make_float4(0.f, 0.f, 0.f, 0.f);
    float mrun = -3e38f, lrun = 0.f;

    const int*   mrow  = mask + ((size_t)(b * TBLK + qrow)) * TBLK;
    const float* kbase = Km + ((size_t)(b * TBLK)) * N_EMBD + h * HEADD;
    const float* vbase = Vm + ((size_t)(b * TBLK)) * N_EMBD + h * HEADD;

    for (int kt = 0; kt < TBLK; kt += 16) {
        __syncthreads();
        {
            int krow = threadIdx.x >> 4;
            int d4   = threadIdx.x & 15;
            ((float4*)Ks)[threadIdx.x] =
                *(const float4*)(kbase + (size_t)(kt + krow) * N_EMBD + d4 * 4);
            ((float4*)Vs)[threadIdx.x] =
                *(const float4*)(vbase + (size_t)(kt + krow) * N_EMBD + d4 * 4);
        }
        __syncthreads();

        float s[16];
        float tmax = -3e38f;
        #pragma unroll
        for (int kk = 0; kk < 16; ++kk) {
            float dot = 0.f;
            #pragma unroll
            for (int j = 0; j < 16; ++j) {
                float4 kv = *(const float4*)&Ks[kk][j * 4];
                dot = fmaf(q[j].x, kv.x, dot);
                dot = fmaf(q[j].y, kv.y, dot);
                dot = fmaf(q[j].z, kv.z, dot);
                dot = fmaf(q[j].w, kv.w, dot);
            }
            dot *= scale;
            int key = kt + kk;
            bool ok = (mrow[key] != 0);
            if (CAUSAL) ok = ok && (key <= qrow);
            s[kk] = ok ? dot : -1e9f;
            tmax = fmaxf(tmax, s[kk]);
        }
        float mnew = fmaxf(mrun, tmax);
        float f = __expf(mrun - mnew);
        lrun *= f;
        #pragma unroll
        for (int j = 0; j < 16; ++j) {
            acc[j].x *= f; acc[j].y *= f; acc[j].z *= f; acc[j].w *= f;
        }
        #pragma unroll
        for (int kk = 0; kk < 16; ++kk) {
            float p = __expf(s[kk] - mnew);
            lrun += p;
            #pragma unroll
            for (int j = 0; j < 16; ++j) {
                float4 vv = *(const float4*)&Vs[kk][j * 4];
                acc[j].x = fmaf(p, vv.x, acc[j].x);
                acc[j].y = fmaf(p, vv.y, acc[j].y);
                acc[j].z = fmaf(p, vv.z, acc[j].z);
                acc[j].w = fmaf(p, vv.w, acc[j].w);
            }
        }
        mrun = mnew;
    }

    float inv = 1.0f / lrun;
    float* op = O + ((size_t)(b * TBLK + qrow)) * N_EMBD + h * HEADD;
    #pragma unroll
    for (int j = 0; j < 16; ++j) {
        float4 o;
        o.x = acc[j].x * inv; o.y = acc[j].y * inv;
        o.z = acc[j].z * inv; o.w = acc[j].w * inv;
        ((float4*)op)[j] = o;
    }
}

// ---------------------------------------------------------------------------
extern "C" void kernel_launch(void* const* d_in, const int* in_sizes, int n_in,
                              void* d_out, int out_size, void* d_ws, size_t ws_size,
                              hipStream_t stream) {
    const float* x    = (const float*)d_in[0];
    const float* ca   = (const float*)d_in[1];
    const int*   x_m  = (const int*)d_in[2];
    const int*   ca_m = (const int*)d_in[3];
    const float* Wq_s = (const float*)d_in[4];
    const float* Wk_s = (const float*)d_in[5];
    const float* Wv_s = (const float*)d_in[6];
    const float* Wo_s = (const float*)d_in[7];
    const float* bo_s = (const float*)d_in[8];
    const float* Wq_c = (const float*)d_in[9];
    const float* Wk_c = (const float*)d_in[10];
    const float* Wv_c = (const float*)d_in[11];
    const float* Wo_c = (const float*)d_in[12];
    const float* bo_c = (const float*)d_in[13];
    const float* g1   = (const float*)d_in[14];
    const float* be1  = (const float*)d_in[15];
    const float* g2   = (const float*)d_in[16];
    const float* be2  = (const float*)d_in[17];
    const float* g3   = (const float*)d_in[18];
    const float* be3  = (const float*)d_in[19];
    const float* Wf1  = (const float*)d_in[20];
    const float* bf1  = (const float*)d_in[21];
    const float* Wf2  = (const float*)d_in[22];
    const float* bf2  = (const float*)d_in[23];

    float* out = (float*)d_out;
    float* ws  = (float*)d_ws;

    const size_t MS = (size_t)MROWS * N_EMBD;   // 8388608 floats (32 MiB)
    // Peak workspace: 4 buffers of MS floats = 128 MiB.
    // LN buffer doubles as ATT output; residual stream lives in d_out;
    // FFN hidden is processed in two 1024-wide chunks aliasing Qb/Kb.
    if (ws_size < 4 * MS * sizeof(float)) {
        // Workspace too small: bail cleanly (diagnostic absmax fail, no fault).
        return;
    }
    float* LN  = ws;            // also ATT
    float* Qb  = ws + MS;
    float* Kb  = ws + 2 * MS;
    float* Vb  = ws + 3 * MS;
    float* FFC = Qb;            // 64 MiB chunk spans Qb..Kb

    dim3 blk(256);
    dim3 gp(N_EMBD / 64, MROWS / 64);           // (8, 256)
    dim3 gh(1024 / 64, MROWS / 64);             // (16, 256)

    // --- self-attention block:  out = x + Attn(LN1(x)) @ Wo + bo ---
    ln_kernel<<<MROWS / 4, blk, 0, stream>>>(x, LN, g1, be1);
    gemm64<<<gp, blk, 0, stream>>>(LN, Wq_s, nullptr, nullptr, Qb, MROWS, N_EMBD, N_EMBD, N_EMBD, N_EMBD, 0);
    gemm64<<<gp, blk, 0, stream>>>(LN, Wk_s, nullptr, nullptr, Kb, MROWS, N_EMBD, N_EMBD, N_EMBD, N_EMBD, 0);
    gemm64<<<gp, blk, 0, stream>>>(LN, Wv_s, nullptr, nullptr, Vb, MROWS, N_EMBD, N_EMBD, N_EMBD, N_EMBD, 0);
    attn_kernel<1><<<BATCH * NHEADS, blk, 0, stream>>>(Qb, Kb, Vb, x_m, LN);
    gemm64<<<gp, blk, 0, stream>>>(LN, Wo_s, bo_s, x, out, MROWS, N_EMBD, N_EMBD, N_EMBD, N_EMBD, 0);

    // --- cross-attention block:  out = out + Attn(LN2(out), ca) @ Wo + bo ---
    ln_kernel<<<MROWS / 4, blk, 0, stream>>>(out, LN, g2, be2);
    gemm64<<<gp, blk, 0, stream>>>(LN, Wq_c, nullptr, nullptr, Qb, MROWS, N_EMBD, N_EMBD, N_EMBD, N_EMBD, 0);
    gemm64<<<gp, blk, 0, stream>>>(ca, Wk_c, nullptr, nullptr, Kb, MROWS, N_EMBD, N_EMBD, N_EMBD, N_EMBD, 0);
    gemm64<<<gp, blk, 0, stream>>>(ca, Wv_c, nullptr, nullptr, Vb, MROWS, N_EMBD, N_EMBD, N_EMBD, N_EMBD, 0);
    attn_kernel<0><<<BATCH * NHEADS, blk, 0, stream>>>(Qb, Kb, Vb, ca_m, LN);
    gemm64<<<gp, blk, 0, stream>>>(LN, Wo_c, bo_c, out, out, MROWS, N_EMBD, N_EMBD, N_EMBD, N_EMBD, 0);

    // --- feed-forward block:  out = out + relu(LN3(out)@Wf1+bf1)@Wf2+bf2 ---
    ln_kernel<<<MROWS / 4, blk, 0, stream>>>(out, LN, g3, be3);
    for (int c = 0; c < 2; ++c) {
        gemm64<<<gh, blk, 0, stream>>>(LN, Wf1 + c * 1024, bf1 + c * 1024, nullptr,
                                       FFC, MROWS, 1024, N_EMBD, FF_DIM, 1024, 1);
        gemm64<<<gp, blk, 0, stream>>>(FFC, Wf2 + (size_t)c * 1024 * N_EMBD,
                                       (c == 0) ? bf2 : nullptr, out, out,
                                       MROWS, N_EMBD, 1024, N_EMBD, N_EMBD, 0);
    }
}

// Round 3
// 1052.550 us; speedup vs baseline: 2.3945x; 2.3945x over previous
//
#include <hip/hip_runtime.h>
#include <hip/hip_bf16.h>
#include <cstddef>

#define N_EMBD 512
#define NHEADS 8
#define HEADD  64
#define TBLK   256
#define BATCH  64
#define FF_DIM 2048
#define MROWS  (BATCH * TBLK)   // 16384

typedef _Float16 half8 __attribute__((ext_vector_type(8)));
typedef _Float16 half4 __attribute__((ext_vector_type(4)));
typedef float    f32x4 __attribute__((ext_vector_type(4)));

#define GLOAD_LDS16(g, l) __builtin_amdgcn_global_load_lds( \
    (const __attribute__((address_space(1))) void*)(g),     \
    (__attribute__((address_space(3))) void*)(l), 16, 0, 0)

// ---------------------------------------------------------------------------
// f32 -> f16 elementwise convert (for ca)
// ---------------------------------------------------------------------------
__global__ __launch_bounds__(256) void conv_f16(
    const float* __restrict__ in, _Float16* __restrict__ out, int n4)
{
    int i = blockIdx.x * 256 + threadIdx.x;
    int stride = gridDim.x * 256;
    for (; i < n4; i += stride) {
        float4 v = ((const float4*)in)[i];
        half4 h;
        h[0] = (_Float16)v.x; h[1] = (_Float16)v.y;
        h[2] = (_Float16)v.z; h[3] = (_Float16)v.w;
        ((half4*)out)[i] = h;
    }
}

// ---------------------------------------------------------------------------
// Weight transpose + convert: W[K][N] f32 -> Wt[N][K] f16. 32x32 LDS tiles.
// ---------------------------------------------------------------------------
__global__ __launch_bounds__(256) void wtrans(
    const float* __restrict__ W, _Float16* __restrict__ Wt, int K, int N)
{
    __shared__ float t[32][33];
    const int n0 = blockIdx.x * 32;
    const int k0 = blockIdx.y * 32;
    const int cx = threadIdx.x & 31;
    const int ry = threadIdx.x >> 5;   // 0..7
    #pragma unroll
    for (int i = 0; i < 4; ++i)
        t[ry + i * 8][cx] = W[(size_t)(k0 + ry + i * 8) * N + n0 + cx];
    __syncthreads();
    #pragma unroll
    for (int i = 0; i < 4; ++i)
        Wt[(size_t)(n0 + ry + i * 8) * K + k0 + cx] = (_Float16)t[cx][ry + i * 8];
}

// ---------------------------------------------------------------------------
// LayerNorm: one wave per row of 512; writes f16.
// ---------------------------------------------------------------------------
__global__ __launch_bounds__(256) void ln_kernel(
    const float* __restrict__ in, _Float16* __restrict__ out,
    const float* __restrict__ g, const float* __restrict__ b)
{
    int row  = blockIdx.x * 4 + (threadIdx.x >> 6);
    int lane = threadIdx.x & 63;
    const float4* r = (const float4*)(in + (size_t)row * N_EMBD);
    float4 v0 = r[lane];
    float4 v1 = r[lane + 64];
    float s  = (v0.x + v0.y) + (v0.z + v0.w) + (v1.x + v1.y) + (v1.z + v1.w);
    float ss = v0.x*v0.x + v0.y*v0.y + v0.z*v0.z + v0.w*v0.w
             + v1.x*v1.x + v1.y*v1.y + v1.z*v1.z + v1.w*v1.w;
    #pragma unroll
    for (int off = 32; off; off >>= 1) {
        s  += __shfl_xor(s, off);
        ss += __shfl_xor(ss, off);
    }
    float mu  = s * (1.0f / 512.0f);
    float var = ss * (1.0f / 512.0f) - mu * mu;
    float rs  = rsqrtf(var + 1e-5f);
    const float4* g4 = (const float4*)g;
    const float4* b4 = (const float4*)b;
    float4 G0 = g4[lane], G1 = g4[lane + 64];
    float4 B0 = b4[lane], B1 = b4[lane + 64];
    half4 h0, h1;
    h0[0] = (_Float16)((v0.x - mu) * rs * G0.x + B0.x);
    h0[1] = (_Float16)((v0.y - mu) * rs * G0.y + B0.y);
    h0[2] = (_Float16)((v0.z - mu) * rs * G0.z + B0.z);
    h0[3] = (_Float16)((v0.w - mu) * rs * G0.w + B0.w);
    h1[0] = (_Float16)((v1.x - mu) * rs * G1.x + B1.x);
    h1[1] = (_Float16)((v1.y - mu) * rs * G1.y + B1.y);
    h1[2] = (_Float16)((v1.z - mu) * rs * G1.z + B1.z);
    h1[3] = (_Float16)((v1.w - mu) * rs * G1.w + B1.w);
    half4* o = (half4*)(out + (size_t)row * N_EMBD);
    o[lane]      = h0;
    o[lane + 64] = h1;
}

// ---------------------------------------------------------------------------
// f16 MFMA GEMM (m97 structure): C[M][N] = A[M][K] @ Bt[N][K]^T
// 128x128 tile, BK=32, 256 threads = 4 waves, each wave 64x64 (4x4 16x16 frags).
// A row stride = K, Bt row stride = ldB, C/resid row stride = N.
// OUTF16: C is f16 (bias/relu optional). else: C f32 with bias+resid.
// ---------------------------------------------------------------------------
template<int OUTF16, int RELU>
__global__ __launch_bounds__(256) void gemm_mfma(
    const _Float16* __restrict__ A, const _Float16* __restrict__ Bt,
    const float* __restrict__ bias, const float* __restrict__ resid,
    void* __restrict__ Cv, int M, int N, int K, int ldB)
{
    __shared__ __attribute__((aligned(16))) _Float16 As[128 * 32];
    __shared__ __attribute__((aligned(16))) _Float16 Bs[128 * 32];
    const int tid  = threadIdx.x;
    const int wid  = tid >> 6;
    const int lane = tid & 63;
    const int row0 = blockIdx.y * 128;
    const int col0 = blockIdx.x * 128;
    const int wr   = (wid >> 1) * 64;
    const int wc   = (wid & 1) * 64;

    // staging: 8 segments of 1KB per matrix; wave w owns segments 2w, 2w+1.
    // lane l of segment s -> LDS half index s*512 + l*8
    //   = row (s*16 + l/4), k ((l&3)*8)   [tile layout row-major [128][32]]
    const int sA   = wid * 2;
    const int lrow = lane >> 2;
    const int lk   = (lane & 3) * 8;
    const _Float16* gA0 = A  + (size_t)(row0 + sA * 16 + lrow)       * K   + lk;
    const _Float16* gA1 = A  + (size_t)(row0 + (sA + 1) * 16 + lrow) * K   + lk;
    const _Float16* gB0 = Bt + (size_t)(col0 + sA * 16 + lrow)       * ldB + lk;
    const _Float16* gB1 = Bt + (size_t)(col0 + (sA + 1) * 16 + lrow) * ldB + lk;
    _Float16* lA0 = As + sA * 512;          // wave-uniform LDS dests
    _Float16* lA1 = As + (sA + 1) * 512;
    _Float16* lB0 = Bs + sA * 512;
    _Float16* lB1 = Bs + (sA + 1) * 512;

    // fragment read base: lane holds row/col (lane&15), k = (lane>>4)*8 ..+7
    const _Float16* fA = As + (size_t)(wr + (lane & 15)) * 32 + (lane >> 4) * 8;
    const _Float16* fB = Bs + (size_t)(wc + (lane & 15)) * 32 + (lane >> 4) * 8;

    f32x4 acc[4][4] = {};

    for (int k0 = 0; k0 < K; k0 += 32) {
        GLOAD_LDS16(gA0 + k0, lA0);
        GLOAD_LDS16(gA1 + k0, lA1);
        GLOAD_LDS16(gB0 + k0, lB0);
        GLOAD_LDS16(gB1 + k0, lB1);
        __syncthreads();
        half8 af[4], bf[4];
        #pragma unroll
        for (int m = 0; m < 4; ++m) af[m] = *(const half8*)(fA + m * 16 * 32);
        #pragma unroll
        for (int n = 0; n < 4; ++n) bf[n] = *(const half8*)(fB + n * 16 * 32);
        #pragma unroll
        for (int m = 0; m < 4; ++m)
            #pragma unroll
            for (int n = 0; n < 4; ++n)
                acc[m][n] = __builtin_amdgcn_mfma_f32_16x16x32_f16(
                    af[m], bf[n], acc[m][n], 0, 0, 0);
        __syncthreads();
    }

    // epilogue: C/D layout col = lane&15, row = (lane>>4)*4 + reg  [m89]
    #pragma unroll
    for (int m = 0; m < 4; ++m) {
        #pragma unroll
        for (int n = 0; n < 4; ++n) {
            #pragma unroll
            for (int r = 0; r < 4; ++r) {
                int row = row0 + wr + m * 16 + (lane >> 4) * 4 + r;
                int col = col0 + wc + n * 16 + (lane & 15);
                float v = acc[m][n][r];
                if (bias) v += bias[col];
                if (RELU) v = fmaxf(v, 0.f);
                if (OUTF16) {
                    ((_Float16*)Cv)[(size_t)row * N + col] = (_Float16)v;
                } else {
                    if (resid) v += resid[(size_t)row * N + col];
                    ((float*)Cv)[(size_t)row * N + col] = v;
                }
            }
        }
    }
}

// ---------------------------------------------------------------------------
// Attention: one single-wave block per (batch, head, 64-row q-tile).
// f16 Q/K/V in, f16 out. Online softmax over 16-key LDS tiles.
// ---------------------------------------------------------------------------
template<int CAUSAL>
__global__ __launch_bounds__(64) void attn_kernel(
    const _Float16* __restrict__ Q, const _Float16* __restrict__ Km,
    const _Float16* __restrict__ Vm, const int* __restrict__ mask,
    _Float16* __restrict__ O)
{
    __shared__ float Ks[16][64];
    __shared__ float Vs[16][64];
    const int blk  = blockIdx.x;
    const int qt   = blk & 3;
    const int bh   = blk >> 2;
    const int b    = bh >> 3;
    const int h    = bh & 7;
    const int lane = threadIdx.x;
    const int qrow = qt * 64 + lane;
    const float scale = 0.04419417382415922f;   // 512^-0.5

    const _Float16* qp = Q + ((size_t)(b * TBLK + qrow)) * N_EMBD + h * HEADD;
    float4 q[16];
    #pragma unroll
    for (int j = 0; j < 8; ++j) {
        half8 hv = ((const half8*)qp)[j];
        q[2*j].x   = (float)hv[0]; q[2*j].y   = (float)hv[1];
        q[2*j].z   = (float)hv[2]; q[2*j].w   = (float)hv[3];
        q[2*j+1].x = (float)hv[4]; q[2*j+1].y = (float)hv[5];
        q[2*j+1].z = (float)hv[6]; q[2*j+1].w = (float)hv[7];
    }

    float4 acc[16];
    #pragma unroll
    for (int j = 0; j < 16; ++j) acc[j] = make_float4(0.f, 0.f, 0.f, 0.f);
    float mrun = -3e38f, lrun = 0.f;

    const int*      mrow  = mask + ((size_t)(b * TBLK + qrow)) * TBLK;
    const _Float16* kbase = Km + ((size_t)(b * TBLK)) * N_EMBD + h * HEADD;
    const _Float16* vbase = Vm + ((size_t)(b * TBLK)) * N_EMBD + h * HEADD;

    const int ktmax = CAUSAL ? (qt + 1) * 64 : TBLK;
    const int r   = lane >> 2;
    const int c16 = (lane & 3) * 16;

    for (int kt = 0; kt < ktmax; kt += 16) {
        __syncthreads();
        {
            const half8* kp = (const half8*)(kbase + (size_t)(kt + r) * N_EMBD + c16);
            const half8* vp = (const half8*)(vbase + (size_t)(kt + r) * N_EMBD + c16);
            half8 kv0 = kp[0], kv1 = kp[1];
            half8 vv0 = vp[0], vv1 = vp[1];
            #pragma unroll
            for (int j = 0; j < 8; ++j) {
                Ks[r][c16 + j]     = (float)kv0[j];
                Ks[r][c16 + 8 + j] = (float)kv1[j];
                Vs[r][c16 + j]     = (float)vv0[j];
                Vs[r][c16 + 8 + j] = (float)vv1[j];
            }
        }
        __syncthreads();

        float s[16];
        float tmax = -3e38f;
        #pragma unroll
        for (int kk = 0; kk < 16; ++kk) {
            float dot = 0.f;
            #pragma unroll
            for (int j = 0; j < 16; ++j) {
                float4 kvv = *(const float4*)&Ks[kk][j * 4];
                dot = fmaf(q[j].x, kvv.x, dot);
                dot = fmaf(q[j].y, kvv.y, dot);
                dot = fmaf(q[j].z, kvv.z, dot);
                dot = fmaf(q[j].w, kvv.w, dot);
            }
            dot *= scale;
            int key = kt + kk;
            bool ok = (mrow[key] != 0);
            if (CAUSAL) ok = ok && (key <= qrow);
            s[kk] = ok ? dot : -1e9f;
            tmax = fmaxf(tmax, s[kk]);
        }
        float mnew = fmaxf(mrun, tmax);
        float f = __expf(mrun - mnew);
        lrun *= f;
        #pragma unroll
        for (int j = 0; j < 16; ++j) {
            acc[j].x *= f; acc[j].y *= f; acc[j].z *= f; acc[j].w *= f;
        }
        #pragma unroll
        for (int kk = 0; kk < 16; ++kk) {
            float p = __expf(s[kk] - mnew);
            lrun += p;
            #pragma unroll
            for (int j = 0; j < 16; ++j) {
                float4 vv = *(const float4*)&Vs[kk][j * 4];
                acc[j].x = fmaf(p, vv.x, acc[j].x);
                acc[j].y = fmaf(p, vv.y, acc[j].y);
                acc[j].z = fmaf(p, vv.z, acc[j].z);
                acc[j].w = fmaf(p, vv.w, acc[j].w);
            }
        }
        mrun = mnew;
    }

    float inv = 1.0f / lrun;
    _Float16* op = O + ((size_t)(b * TBLK + qrow)) * N_EMBD + h * HEADD;
    #pragma unroll
    for (int j = 0; j < 8; ++j) {
        half8 hv;
        hv[0] = (_Float16)(acc[2*j].x   * inv);
        hv[1] = (_Float16)(acc[2*j].y   * inv);
        hv[2] = (_Float16)(acc[2*j].z   * inv);
        hv[3] = (_Float16)(acc[2*j].w   * inv);
        hv[4] = (_Float16)(acc[2*j+1].x * inv);
        hv[5] = (_Float16)(acc[2*j+1].y * inv);
        hv[6] = (_Float16)(acc[2*j+1].z * inv);
        hv[7] = (_Float16)(acc[2*j+1].w * inv);
        ((half8*)op)[j] = hv;
    }
}

// ---------------------------------------------------------------------------
extern "C" void kernel_launch(void* const* d_in, const int* in_sizes, int n_in,
                              void* d_out, int out_size, void* d_ws, size_t ws_size,
                              hipStream_t stream) {
    const float* x    = (const float*)d_in[0];
    const float* ca   = (const float*)d_in[1];
    const int*   x_m  = (const int*)d_in[2];
    const int*   ca_m = (const int*)d_in[3];
    const float* Wq_s = (const float*)d_in[4];
    const float* Wk_s = (const float*)d_in[5];
    const float* Wv_s = (const float*)d_in[6];
    const float* Wo_s = (const float*)d_in[7];
    const float* bo_s = (const float*)d_in[8];
    const float* Wq_c = (const float*)d_in[9];
    const float* Wk_c = (const float*)d_in[10];
    const float* Wv_c = (const float*)d_in[11];
    const float* Wo_c = (const float*)d_in[12];
    const float* bo_c = (const float*)d_in[13];
    const float* g1   = (const float*)d_in[14];
    const float* be1  = (const float*)d_in[15];
    const float* g2   = (const float*)d_in[16];
    const float* be2  = (const float*)d_in[17];
    const float* g3   = (const float*)d_in[18];
    const float* be3  = (const float*)d_in[19];
    const float* Wf1  = (const float*)d_in[20];
    const float* bf1  = (const float*)d_in[21];
    const float* Wf2  = (const float*)d_in[22];
    const float* bf2  = (const float*)d_in[23];

    float* out = (float*)d_out;
    char*  ws  = (char*)d_ws;

    const size_t MiB = 1024 * 1024;
    if (ws_size < 90 * MiB) return;   // need 88 MiB

    _Float16* LNh  = (_Float16*)(ws);             // 16 MiB; also ATT out
    _Float16* Qh   = (_Float16*)(ws + 16 * MiB);  // 16 MiB
    _Float16* Kh   = (_Float16*)(ws + 32 * MiB);  // 16 MiB
    _Float16* Vh   = (_Float16*)(ws + 48 * MiB);  // 16 MiB
    _Float16* cah  = (_Float16*)(ws + 64 * MiB);  // 16 MiB
    _Float16* wqs  = (_Float16*)(ws + 80 * MiB);  // 8 x 512 KiB
    _Float16* wks  = wqs + 262144;
    _Float16* wvs  = wks + 262144;
    _Float16* wos  = wvs + 262144;
    _Float16* wqc  = wos + 262144;
    _Float16* wkc  = wqc + 262144;
    _Float16* wvc  = wkc + 262144;
    _Float16* woc  = wvc + 262144;
    _Float16* wf1t = (_Float16*)(ws + 84 * MiB);  // [2048][512] 2 MiB
    _Float16* wf2t = (_Float16*)(ws + 86 * MiB);  // [512][2048] 2 MiB
    _Float16* FFC  = Qh;                          // 32 MiB spans Qh..Kh

    dim3 blk(256);
    dim3 g5(16, 16);                 // 512x512 transpose
    // weight conversion (every call: inputs are re-poisoned/restored)
    wtrans<<<g5, blk, 0, stream>>>(Wq_s, wqs, N_EMBD, N_EMBD);
    wtrans<<<g5, blk, 0, stream>>>(Wk_s, wks, N_EMBD, N_EMBD);
    wtrans<<<g5, blk, 0, stream>>>(Wv_s, wvs, N_EMBD, N_EMBD);
    wtrans<<<g5, blk, 0, stream>>>(Wo_s, wos, N_EMBD, N_EMBD);
    wtrans<<<g5, blk, 0, stream>>>(Wq_c, wqc, N_EMBD, N_EMBD);
    wtrans<<<g5, blk, 0, stream>>>(Wk_c, wkc, N_EMBD, N_EMBD);
    wtrans<<<g5, blk, 0, stream>>>(Wv_c, wvc, N_EMBD, N_EMBD);
    wtrans<<<g5, blk, 0, stream>>>(Wo_c, woc, N_EMBD, N_EMBD);
    wtrans<<<dim3(FF_DIM / 32, N_EMBD / 32), blk, 0, stream>>>(Wf1, wf1t, N_EMBD, FF_DIM);
    wtrans<<<dim3(N_EMBD / 32, FF_DIM / 32), blk, 0, stream>>>(Wf2, wf2t, FF_DIM, N_EMBD);
    conv_f16<<<2048, blk, 0, stream>>>(ca, cah, MROWS * N_EMBD / 4);

    dim3 gp(N_EMBD / 128, MROWS / 128);   // (4, 128)
    dim3 gh(1024 / 128,  MROWS / 128);    // (8, 128)
    dim3 ga(BATCH * NHEADS * 4);

    // --- self-attention: out = x + Attn(LN1(x)) @ Wo + bo ---
    ln_kernel<<<MROWS / 4, blk, 0, stream>>>(x, LNh, g1, be1);
    gemm_mfma<1,0><<<gp, blk, 0, stream>>>(LNh, wqs, nullptr, nullptr, Qh, MROWS, N_EMBD, N_EMBD, N_EMBD);
    gemm_mfma<1,0><<<gp, blk, 0, stream>>>(LNh, wks, nullptr, nullptr, Kh, MROWS, N_EMBD, N_EMBD, N_EMBD);
    gemm_mfma<1,0><<<gp, blk, 0, stream>>>(LNh, wvs, nullptr, nullptr, Vh, MROWS, N_EMBD, N_EMBD, N_EMBD);
    attn_kernel<1><<<ga, dim3(64), 0, stream>>>(Qh, Kh, Vh, x_m, LNh);
    gemm_mfma<0,0><<<gp, blk, 0, stream>>>(LNh, wos, bo_s, x, out, MROWS, N_EMBD, N_EMBD, N_EMBD);

    // --- cross-attention: out = out + Attn(LN2(out), ca) @ Wo + bo ---
    ln_kernel<<<MROWS / 4, blk, 0, stream>>>(out, LNh, g2, be2);
    gemm_mfma<1,0><<<gp, blk, 0, stream>>>(LNh, wqc, nullptr, nullptr, Qh, MROWS, N_EMBD, N_EMBD, N_EMBD);
    gemm_mfma<1,0><<<gp, blk, 0, stream>>>(cah, wkc, nullptr, nullptr, Kh, MROWS, N_EMBD, N_EMBD, N_EMBD);
    gemm_mfma<1,0><<<gp, blk, 0, stream>>>(cah, wvc, nullptr, nullptr, Vh, MROWS, N_EMBD, N_EMBD, N_EMBD);
    attn_kernel<0><<<ga, dim3(64), 0, stream>>>(Qh, Kh, Vh, ca_m, LNh);
    gemm_mfma<0,0><<<gp, blk, 0, stream>>>(LNh, woc, bo_c, out, out, MROWS, N_EMBD, N_EMBD, N_EMBD);

    // --- FFN: out = out + relu(LN3(out)@Wf1+bf1)@Wf2+bf2  (2 chunks of 1024) ---
    ln_kernel<<<MROWS / 4, blk, 0, stream>>>(out, LNh, g3, be3);
    for (int c = 0; c < 2; ++c) {
        gemm_mfma<1,1><<<gh, blk, 0, stream>>>(LNh, wf1t + (size_t)c * 1024 * N_EMBD,
                                               bf1 + c * 1024, nullptr, FFC,
                                               MROWS, 1024, N_EMBD, N_EMBD);
        gemm_mfma<0,0><<<gp, blk, 0, stream>>>(FFC, wf2t + (size_t)c * 1024,
                                               (c == 0) ? bf2 : nullptr, out, out,
                                               MROWS, N_EMBD, 1024, FF_DIM);
    }
}

// Round 4
// 843.202 us; speedup vs baseline: 2.9890x; 1.2483x over previous
//
#include <hip/hip_runtime.h>
#include <hip/hip_bf16.h>
#include <cstddef>

#define N_EMBD 512
#define NHEADS 8
#define HEADD  64
#define TBLK   256
#define BATCH  64
#define FF_DIM 2048
#define MROWS  (BATCH * TBLK)   // 16384

typedef _Float16 half8 __attribute__((ext_vector_type(8)));
typedef _Float16 half4 __attribute__((ext_vector_type(4)));
typedef float    f32x4 __attribute__((ext_vector_type(4)));

#define GLOAD_LDS16(g, l) __builtin_amdgcn_global_load_lds( \
    (const __attribute__((address_space(1))) void*)(g),     \
    (__attribute__((address_space(3))) void*)(l), 16, 0, 0)

// ---------------------------------------------------------------------------
// f32 -> f16 elementwise convert (for ca)
// ---------------------------------------------------------------------------
__global__ __launch_bounds__(256) void conv_f16(
    const float* __restrict__ in, _Float16* __restrict__ out, int n4)
{
    int i = blockIdx.x * 256 + threadIdx.x;
    int stride = gridDim.x * 256;
    for (; i < n4; i += stride) {
        float4 v = ((const float4*)in)[i];
        half4 h;
        h[0] = (_Float16)v.x; h[1] = (_Float16)v.y;
        h[2] = (_Float16)v.z; h[3] = (_Float16)v.w;
        ((half4*)out)[i] = h;
    }
}

// ---------------------------------------------------------------------------
// mask flag: flag stays nonzero iff ALL mask entries are nonzero.
// ---------------------------------------------------------------------------
__global__ void flag_init(unsigned* f) {
    if (threadIdx.x < 2) f[threadIdx.x] = 0xFFFFFFFFu;
}
__global__ __launch_bounds__(256) void mask_check(
    const int* __restrict__ m, int n, unsigned* __restrict__ flag)
{
    int i = blockIdx.x * 256 + threadIdx.x;
    const int stride = gridDim.x * 256;
    bool ok = true;
    for (; i < n; i += stride) ok = ok && (m[i] != 0);
    if (!__all(ok)) {
        if ((threadIdx.x & 63) == 0) atomicAnd(flag, 0u);
    }
}

// ---------------------------------------------------------------------------
// Weight transpose + convert: W[K][N] f32 -> Wt[N][K] f16. 32x32 LDS tiles.
// ---------------------------------------------------------------------------
__global__ __launch_bounds__(256) void wtrans(
    const float* __restrict__ W, _Float16* __restrict__ Wt, int K, int N)
{
    __shared__ float t[32][33];
    const int n0 = blockIdx.x * 32;
    const int k0 = blockIdx.y * 32;
    const int cx = threadIdx.x & 31;
    const int ry = threadIdx.x >> 5;   // 0..7
    #pragma unroll
    for (int i = 0; i < 4; ++i)
        t[ry + i * 8][cx] = W[(size_t)(k0 + ry + i * 8) * N + n0 + cx];
    __syncthreads();
    #pragma unroll
    for (int i = 0; i < 4; ++i)
        Wt[(size_t)(n0 + ry + i * 8) * K + k0 + cx] = (_Float16)t[cx][ry + i * 8];
}

// ---------------------------------------------------------------------------
// LayerNorm: one wave per row of 512; writes f16.
// ---------------------------------------------------------------------------
__global__ __launch_bounds__(256) void ln_kernel(
    const float* __restrict__ in, _Float16* __restrict__ out,
    const float* __restrict__ g, const float* __restrict__ b)
{
    int row  = blockIdx.x * 4 + (threadIdx.x >> 6);
    int lane = threadIdx.x & 63;
    const float4* r = (const float4*)(in + (size_t)row * N_EMBD);
    float4 v0 = r[lane];
    float4 v1 = r[lane + 64];
    float s  = (v0.x + v0.y) + (v0.z + v0.w) + (v1.x + v1.y) + (v1.z + v1.w);
    float ss = v0.x*v0.x + v0.y*v0.y + v0.z*v0.z + v0.w*v0.w
             + v1.x*v1.x + v1.y*v1.y + v1.z*v1.z + v1.w*v1.w;
    #pragma unroll
    for (int off = 32; off; off >>= 1) {
        s  += __shfl_xor(s, off);
        ss += __shfl_xor(ss, off);
    }
    float mu  = s * (1.0f / 512.0f);
    float var = ss * (1.0f / 512.0f) - mu * mu;
    float rs  = rsqrtf(var + 1e-5f);
    const float4* g4 = (const float4*)g;
    const float4* b4 = (const float4*)b;
    float4 G0 = g4[lane], G1 = g4[lane + 64];
    float4 B0 = b4[lane], B1 = b4[lane + 64];
    half4 h0, h1;
    h0[0] = (_Float16)((v0.x - mu) * rs * G0.x + B0.x);
    h0[1] = (_Float16)((v0.y - mu) * rs * G0.y + B0.y);
    h0[2] = (_Float16)((v0.z - mu) * rs * G0.z + B0.z);
    h0[3] = (_Float16)((v0.w - mu) * rs * G0.w + B0.w);
    h1[0] = (_Float16)((v1.x - mu) * rs * G1.x + B1.x);
    h1[1] = (_Float16)((v1.y - mu) * rs * G1.y + B1.y);
    h1[2] = (_Float16)((v1.z - mu) * rs * G1.z + B1.z);
    h1[3] = (_Float16)((v1.w - mu) * rs * G1.w + B1.w);
    half4* o = (half4*)(out + (size_t)row * N_EMBD);
    o[lane]      = h0;
    o[lane + 64] = h1;
}

// ---------------------------------------------------------------------------
// f16 MFMA GEMM (m97 structure): C[M][N] = A[M][K] @ Bt[N][K]^T
// ---------------------------------------------------------------------------
template<int OUTF16, int RELU>
__global__ __launch_bounds__(256) void gemm_mfma(
    const _Float16* __restrict__ A, const _Float16* __restrict__ Bt,
    const float* __restrict__ bias, const float* __restrict__ resid,
    void* __restrict__ Cv, int M, int N, int K, int ldB)
{
    __shared__ __attribute__((aligned(16))) _Float16 As[128 * 32];
    __shared__ __attribute__((aligned(16))) _Float16 Bs[128 * 32];
    const int tid  = threadIdx.x;
    const int wid  = tid >> 6;
    const int lane = tid & 63;
    const int row0 = blockIdx.y * 128;
    const int col0 = blockIdx.x * 128;
    const int wr   = (wid >> 1) * 64;
    const int wc   = (wid & 1) * 64;

    const int sA   = wid * 2;
    const int lrow = lane >> 2;
    const int lk   = (lane & 3) * 8;
    const _Float16* gA0 = A  + (size_t)(row0 + sA * 16 + lrow)       * K   + lk;
    const _Float16* gA1 = A  + (size_t)(row0 + (sA + 1) * 16 + lrow) * K   + lk;
    const _Float16* gB0 = Bt + (size_t)(col0 + sA * 16 + lrow)       * ldB + lk;
    const _Float16* gB1 = Bt + (size_t)(col0 + (sA + 1) * 16 + lrow) * ldB + lk;
    _Float16* lA0 = As + sA * 512;
    _Float16* lA1 = As + (sA + 1) * 512;
    _Float16* lB0 = Bs + sA * 512;
    _Float16* lB1 = Bs + (sA + 1) * 512;

    const _Float16* fA = As + (size_t)(wr + (lane & 15)) * 32 + (lane >> 4) * 8;
    const _Float16* fB = Bs + (size_t)(wc + (lane & 15)) * 32 + (lane >> 4) * 8;

    f32x4 acc[4][4] = {};

    for (int k0 = 0; k0 < K; k0 += 32) {
        GLOAD_LDS16(gA0 + k0, lA0);
        GLOAD_LDS16(gA1 + k0, lA1);
        GLOAD_LDS16(gB0 + k0, lB0);
        GLOAD_LDS16(gB1 + k0, lB1);
        __syncthreads();
        half8 af[4], bf[4];
        #pragma unroll
        for (int m = 0; m < 4; ++m) af[m] = *(const half8*)(fA + m * 16 * 32);
        #pragma unroll
        for (int n = 0; n < 4; ++n) bf[n] = *(const half8*)(fB + n * 16 * 32);
        #pragma unroll
        for (int m = 0; m < 4; ++m)
            #pragma unroll
            for (int n = 0; n < 4; ++n)
                acc[m][n] = __builtin_amdgcn_mfma_f32_16x16x32_f16(
                    af[m], bf[n], acc[m][n], 0, 0, 0);
        __syncthreads();
    }

    #pragma unroll
    for (int m = 0; m < 4; ++m) {
        #pragma unroll
        for (int n = 0; n < 4; ++n) {
            #pragma unroll
            for (int r = 0; r < 4; ++r) {
                int row = row0 + wr + m * 16 + (lane >> 4) * 4 + r;
                int col = col0 + wc + n * 16 + (lane & 15);
                float v = acc[m][n][r];
                if (bias) v += bias[col];
                if (RELU) v = fmaxf(v, 0.f);
                if (OUTF16) {
                    ((_Float16*)Cv)[(size_t)row * N + col] = (_Float16)v;
                } else {
                    if (resid) v += resid[(size_t)row * N + col];
                    ((float*)Cv)[(size_t)row * N + col] = v;
                }
            }
        }
    }
}

// ---------------------------------------------------------------------------
// MFMA flash-attention. One block per (batch, head); 4 waves x 64 q-rows.
// K staged [32][88] f16 (padded); V staged transposed [64][40]; P round-trips
// through per-wave LDS [64][40] to convert C-layout -> A-frag layout.
// Fast path when mask flag says "all nonzero" (causal via index compare).
// ---------------------------------------------------------------------------
template<int CAUSAL>
__global__ __launch_bounds__(256) void attn_mfma(
    const _Float16* __restrict__ Q, const _Float16* __restrict__ Km,
    const _Float16* __restrict__ Vm, const int* __restrict__ mask,
    const unsigned* __restrict__ flagp, _Float16* __restrict__ O)
{
    __shared__ __attribute__((aligned(16))) _Float16 Ks[32 * 88];
    __shared__ __attribute__((aligned(16))) _Float16 Vt[64 * 40];
    __shared__ __attribute__((aligned(16))) _Float16 Pl[4][64 * 40];

    const int bh   = blockIdx.x;
    const int b    = bh >> 3;
    const int h    = bh & 7;
    const int tid  = threadIdx.x;
    const int wid  = tid >> 6;
    const int lane = tid & 63;
    const int l15  = lane & 15;
    const int kg8  = (lane >> 4) * 8;
    const int q0   = wid * 64;
    const unsigned allones = flagp[0];
    const float scale = 0.04419417382415922f;   // 512^-0.5

    // Q fragments (held in registers for the whole kernel)
    half8 af[4][2];
    #pragma unroll
    for (int m = 0; m < 4; ++m)
        #pragma unroll
        for (int c = 0; c < 2; ++c)
            af[m][c] = *(const half8*)(Q + (size_t)(b * TBLK + q0 + m * 16 + l15) * N_EMBD
                                         + h * HEADD + c * 32 + kg8);

    f32x4 o[4][4] = {};
    float mrun[4][4], lrun[4][4];
    #pragma unroll
    for (int m = 0; m < 4; ++m)
        #pragma unroll
        for (int r = 0; r < 4; ++r) { mrun[m][r] = -1e30f; lrun[m][r] = 0.f; }

    _Float16* PlW = Pl[wid];
    const int srow = tid >> 3;       // 0..31
    const int sc   = tid & 7;        // 0..7
    const _Float16* kgp = Km + (size_t)(b * TBLK) * N_EMBD + h * HEADD;
    const _Float16* vgp = Vm + (size_t)(b * TBLK) * N_EMBD + h * HEADD;
    const int kmax_w = CAUSAL ? q0 + 64 : TBLK;

    for (int kt = 0; kt < TBLK; kt += 32) {
        __syncthreads();
        {
            half8 kv = *(const half8*)(kgp + (size_t)(kt + srow) * N_EMBD + sc * 8);
            half8 vv = *(const half8*)(vgp + (size_t)(kt + srow) * N_EMBD + sc * 8);
            *(half8*)&Ks[srow * 88 + sc * 8] = kv;
            #pragma unroll
            for (int j = 0; j < 8; ++j)
                Vt[(sc * 8 + j) * 40 + srow] = vv[j];
        }
        __syncthreads();
        if (!CAUSAL || kt < kmax_w) {
            // S = Q @ K^T for this 64q x 32k tile
            f32x4 s[4][2] = {};
            #pragma unroll
            for (int c = 0; c < 2; ++c) {
                half8 bk0 = *(const half8*)&Ks[(l15)      * 88 + c * 32 + kg8];
                half8 bk1 = *(const half8*)&Ks[(16 + l15) * 88 + c * 32 + kg8];
                #pragma unroll
                for (int m = 0; m < 4; ++m) {
                    s[m][0] = __builtin_amdgcn_mfma_f32_16x16x32_f16(af[m][c], bk0, s[m][0], 0, 0, 0);
                    s[m][1] = __builtin_amdgcn_mfma_f32_16x16x32_f16(af[m][c], bk1, s[m][1], 0, 0, 0);
                }
            }
            // online softmax, wave-parallel (row = m*16 + (lane>>4)*4 + r)
            #pragma unroll
            for (int m = 0; m < 4; ++m) {
                #pragma unroll
                for (int r = 0; r < 4; ++r) {
                    float s0 = s[m][0][r] * scale;
                    float s1 = s[m][1][r] * scale;
                    const int qrow = q0 + m * 16 + (lane >> 4) * 4 + r;
                    if (!allones) {
                        const int* mr = mask + (size_t)(b * TBLK + qrow) * TBLK + kt;
                        if (mr[l15] == 0)      s0 = -1e9f;
                        if (mr[16 + l15] == 0) s1 = -1e9f;
                    }
                    if (CAUSAL) {
                        if (kt + l15 > qrow)      s0 = -1e9f;
                        if (kt + 16 + l15 > qrow) s1 = -1e9f;
                    }
                    float tm = fmaxf(s0, s1);
                    tm = fmaxf(tm, __shfl_xor(tm, 1));
                    tm = fmaxf(tm, __shfl_xor(tm, 2));
                    tm = fmaxf(tm, __shfl_xor(tm, 4));
                    tm = fmaxf(tm, __shfl_xor(tm, 8));
                    float mnew = fmaxf(mrun[m][r], tm);
                    float fr = __expf(mrun[m][r] - mnew);
                    float p0 = __expf(s0 - mnew);
                    float p1 = __expf(s1 - mnew);
                    float rs = p0 + p1;
                    rs += __shfl_xor(rs, 1);
                    rs += __shfl_xor(rs, 2);
                    rs += __shfl_xor(rs, 4);
                    rs += __shfl_xor(rs, 8);
                    lrun[m][r] = lrun[m][r] * fr + rs;
                    mrun[m][r] = mnew;
                    o[m][0][r] *= fr; o[m][1][r] *= fr;
                    o[m][2][r] *= fr; o[m][3][r] *= fr;
                    _Float16* pw = PlW + (m * 16 + (lane >> 4) * 4 + r) * 40;
                    pw[l15]      = (_Float16)p0;
                    pw[16 + l15] = (_Float16)p1;
                }
            }
            // O += P @ V  (A-frag from P_lds, B-frag from transposed V)
            half8 pa[4];
            #pragma unroll
            for (int m = 0; m < 4; ++m)
                pa[m] = *(const half8*)&PlW[(m * 16 + l15) * 40 + kg8];
            #pragma unroll
            for (int dn = 0; dn < 4; ++dn) {
                half8 bv = *(const half8*)&Vt[(dn * 16 + l15) * 40 + kg8];
                #pragma unroll
                for (int m = 0; m < 4; ++m)
                    o[m][dn] = __builtin_amdgcn_mfma_f32_16x16x32_f16(pa[m], bv, o[m][dn], 0, 0, 0);
            }
        }
    }

    #pragma unroll
    for (int m = 0; m < 4; ++m) {
        #pragma unroll
        for (int r = 0; r < 4; ++r) {
            float inv = 1.0f / lrun[m][r];
            const int qrow = q0 + m * 16 + (lane >> 4) * 4 + r;
            _Float16* op = O + (size_t)(b * TBLK + qrow) * N_EMBD + h * HEADD;
            #pragma unroll
            for (int dn = 0; dn < 4; ++dn)
                op[dn * 16 + l15] = (_Float16)(o[m][dn][r] * inv);
        }
    }
}

// ---------------------------------------------------------------------------
extern "C" void kernel_launch(void* const* d_in, const int* in_sizes, int n_in,
                              void* d_out, int out_size, void* d_ws, size_t ws_size,
                              hipStream_t stream) {
    const float* x    = (const float*)d_in[0];
    const float* ca   = (const float*)d_in[1];
    const int*   x_m  = (const int*)d_in[2];
    const int*   ca_m = (const int*)d_in[3];
    const float* Wq_s = (const float*)d_in[4];
    const float* Wk_s = (const float*)d_in[5];
    const float* Wv_s = (const float*)d_in[6];
    const float* Wo_s = (const float*)d_in[7];
    const float* bo_s = (const float*)d_in[8];
    const float* Wq_c = (const float*)d_in[9];
    const float* Wk_c = (const float*)d_in[10];
    const float* Wv_c = (const float*)d_in[11];
    const float* Wo_c = (const float*)d_in[12];
    const float* bo_c = (const float*)d_in[13];
    const float* g1   = (const float*)d_in[14];
    const float* be1  = (const float*)d_in[15];
    const float* g2   = (const float*)d_in[16];
    const float* be2  = (const float*)d_in[17];
    const float* g3   = (const float*)d_in[18];
    const float* be3  = (const float*)d_in[19];
    const float* Wf1  = (const float*)d_in[20];
    const float* bf1  = (const float*)d_in[21];
    const float* Wf2  = (const float*)d_in[22];
    const float* bf2  = (const float*)d_in[23];

    float* out = (float*)d_out;
    char*  ws  = (char*)d_ws;

    const size_t MiB = 1024 * 1024;
    if (ws_size < 90 * MiB) return;

    _Float16* LNh  = (_Float16*)(ws);             // 16 MiB; also ATT out
    _Float16* Qh   = (_Float16*)(ws + 16 * MiB);
    _Float16* Kh   = (_Float16*)(ws + 32 * MiB);
    _Float16* Vh   = (_Float16*)(ws + 48 * MiB);
    _Float16* cah  = (_Float16*)(ws + 64 * MiB);
    _Float16* wqs  = (_Float16*)(ws + 80 * MiB);
    _Float16* wks  = wqs + 262144;
    _Float16* wvs  = wks + 262144;
    _Float16* wos  = wvs + 262144;
    _Float16* wqc  = wos + 262144;
    _Float16* wkc  = wqc + 262144;
    _Float16* wvc  = wkc + 262144;
    _Float16* woc  = wvc + 262144;
    _Float16* wf1t = (_Float16*)(ws + 84 * MiB);
    _Float16* wf2t = (_Float16*)(ws + 86 * MiB);
    unsigned* flags = (unsigned*)(ws + 89 * MiB); // [0]=x_m, [1]=ca_m
    _Float16* FFC  = Qh;                          // 32 MiB spans Qh..Kh

    dim3 blk(256);
    dim3 g5(16, 16);
    flag_init<<<1, 64, 0, stream>>>(flags);
    mask_check<<<1024, blk, 0, stream>>>(x_m,  MROWS * TBLK, flags);
    mask_check<<<1024, blk, 0, stream>>>(ca_m, MROWS * TBLK, flags + 1);

    wtrans<<<g5, blk, 0, stream>>>(Wq_s, wqs, N_EMBD, N_EMBD);
    wtrans<<<g5, blk, 0, stream>>>(Wk_s, wks, N_EMBD, N_EMBD);
    wtrans<<<g5, blk, 0, stream>>>(Wv_s, wvs, N_EMBD, N_EMBD);
    wtrans<<<g5, blk, 0, stream>>>(Wo_s, wos, N_EMBD, N_EMBD);
    wtrans<<<g5, blk, 0, stream>>>(Wq_c, wqc, N_EMBD, N_EMBD);
    wtrans<<<g5, blk, 0, stream>>>(Wk_c, wkc, N_EMBD, N_EMBD);
    wtrans<<<g5, blk, 0, stream>>>(Wv_c, wvc, N_EMBD, N_EMBD);
    wtrans<<<g5, blk, 0, stream>>>(Wo_c, woc, N_EMBD, N_EMBD);
    wtrans<<<dim3(FF_DIM / 32, N_EMBD / 32), blk, 0, stream>>>(Wf1, wf1t, N_EMBD, FF_DIM);
    wtrans<<<dim3(N_EMBD / 32, FF_DIM / 32), blk, 0, stream>>>(Wf2, wf2t, FF_DIM, N_EMBD);
    conv_f16<<<2048, blk, 0, stream>>>(ca, cah, MROWS * N_EMBD / 4);

    dim3 gp(N_EMBD / 128, MROWS / 128);   // (4, 128)
    dim3 gh(1024 / 128,  MROWS / 128);    // (8, 128)
    dim3 ga(BATCH * NHEADS);

    // --- self-attention: out = x + Attn(LN1(x)) @ Wo + bo ---
    ln_kernel<<<MROWS / 4, blk, 0, stream>>>(x, LNh, g1, be1);
    gemm_mfma<1,0><<<gp, blk, 0, stream>>>(LNh, wqs, nullptr, nullptr, Qh, MROWS, N_EMBD, N_EMBD, N_EMBD);
    gemm_mfma<1,0><<<gp, blk, 0, stream>>>(LNh, wks, nullptr, nullptr, Kh, MROWS, N_EMBD, N_EMBD, N_EMBD);
    gemm_mfma<1,0><<<gp, blk, 0, stream>>>(LNh, wvs, nullptr, nullptr, Vh, MROWS, N_EMBD, N_EMBD, N_EMBD);
    attn_mfma<1><<<ga, blk, 0, stream>>>(Qh, Kh, Vh, x_m, flags, LNh);
    gemm_mfma<0,0><<<gp, blk, 0, stream>>>(LNh, wos, bo_s, x, out, MROWS, N_EMBD, N_EMBD, N_EMBD);

    // --- cross-attention: out = out + Attn(LN2(out), ca) @ Wo + bo ---
    ln_kernel<<<MROWS / 4, blk, 0, stream>>>(out, LNh, g2, be2);
    gemm_mfma<1,0><<<gp, blk, 0, stream>>>(LNh, wqc, nullptr, nullptr, Qh, MROWS, N_EMBD, N_EMBD, N_EMBD);
    gemm_mfma<1,0><<<gp, blk, 0, stream>>>(cah, wkc, nullptr, nullptr, Kh, MROWS, N_EMBD, N_EMBD, N_EMBD);
    gemm_mfma<1,0><<<gp, blk, 0, stream>>>(cah, wvc, nullptr, nullptr, Vh, MROWS, N_EMBD, N_EMBD, N_EMBD);
    attn_mfma<0><<<ga, blk, 0, stream>>>(Qh, Kh, Vh, ca_m, flags + 1, LNh);
    gemm_mfma<0,0><<<gp, blk, 0, stream>>>(LNh, woc, bo_c, out, out, MROWS, N_EMBD, N_EMBD, N_EMBD);

    // --- FFN: out = out + relu(LN3(out)@Wf1+bf1)@Wf2+bf2  (2 chunks of 1024) ---
    ln_kernel<<<MROWS / 4, blk, 0, stream>>>(out, LNh, g3, be3);
    for (int c = 0; c < 2; ++c) {
        gemm_mfma<1,1><<<gh, blk, 0, stream>>>(LNh, wf1t + (size_t)c * 1024 * N_EMBD,
                                               bf1 + c * 1024, nullptr, FFC,
                                               MROWS, 1024, N_EMBD, N_EMBD);
        gemm_mfma<0,0><<<gp, blk, 0, stream>>>(FFC, wf2t + (size_t)c * 1024,
                                               (c == 0) ? bf2 : nullptr, out, out,
                                               MROWS, N_EMBD, 1024, FF_DIM);
    }
}

// Round 5
// 717.247 us; speedup vs baseline: 3.5139x; 1.1756x over previous
//
#include <hip/hip_runtime.h>
#include <hip/hip_bf16.h>
#include <cstddef>

#define N_EMBD 512
#define NHEADS 8
#define HEADD  64
#define TBLK   256
#define BATCH  64
#define FF_DIM 2048
#define MROWS  (BATCH * TBLK)   // 16384

typedef _Float16 half8 __attribute__((ext_vector_type(8)));
typedef _Float16 half4 __attribute__((ext_vector_type(4)));
typedef float    f32x4 __attribute__((ext_vector_type(4)));

#define GLOAD_LDS16(g, l) __builtin_amdgcn_global_load_lds( \
    (const __attribute__((address_space(1))) void*)(g),     \
    (__attribute__((address_space(3))) void*)(l), 16, 0, 0)

// ---------------------------------------------------------------------------
// f32 -> f16 elementwise convert (for ca)
// ---------------------------------------------------------------------------
__global__ __launch_bounds__(256) void conv_f16(
    const float* __restrict__ in, _Float16* __restrict__ out, int n4)
{
    int i = blockIdx.x * 256 + threadIdx.x;
    int stride = gridDim.x * 256;
    for (; i < n4; i += stride) {
        float4 v = ((const float4*)in)[i];
        half4 h;
        h[0] = (_Float16)v.x; h[1] = (_Float16)v.y;
        h[2] = (_Float16)v.z; h[3] = (_Float16)v.w;
        ((half4*)out)[i] = h;
    }
}

// ---------------------------------------------------------------------------
// mask flag: flag stays nonzero iff ALL mask entries are nonzero.
// ---------------------------------------------------------------------------
__global__ void flag_init(unsigned* f) {
    if (threadIdx.x < 2) f[threadIdx.x] = 0xFFFFFFFFu;
}
__global__ __launch_bounds__(256) void mask_check(
    const int* __restrict__ m, int n, unsigned* __restrict__ flag)
{
    int i = blockIdx.x * 256 + threadIdx.x;
    const int stride = gridDim.x * 256;
    bool ok = true;
    for (; i < n; i += stride) ok = ok && (m[i] != 0);
    if (!__all(ok)) {
        if ((threadIdx.x & 63) == 0) atomicAnd(flag, 0u);
    }
}

// ---------------------------------------------------------------------------
// Weight transpose + convert: W[K][N] f32 -> Wt[N][K] f16. 32x32 LDS tiles.
// ---------------------------------------------------------------------------
__global__ __launch_bounds__(256) void wtrans(
    const float* __restrict__ W, _Float16* __restrict__ Wt, int K, int N)
{
    __shared__ float t[32][33];
    const int n0 = blockIdx.x * 32;
    const int k0 = blockIdx.y * 32;
    const int cx = threadIdx.x & 31;
    const int ry = threadIdx.x >> 5;   // 0..7
    #pragma unroll
    for (int i = 0; i < 4; ++i)
        t[ry + i * 8][cx] = W[(size_t)(k0 + ry + i * 8) * N + n0 + cx];
    __syncthreads();
    #pragma unroll
    for (int i = 0; i < 4; ++i)
        Wt[(size_t)(n0 + ry + i * 8) * K + k0 + cx] = (_Float16)t[cx][ry + i * 8];
}

// ---------------------------------------------------------------------------
// LayerNorm: one wave per row of 512; writes f16.
// ---------------------------------------------------------------------------
__global__ __launch_bounds__(256) void ln_kernel(
    const float* __restrict__ in, _Float16* __restrict__ out,
    const float* __restrict__ g, const float* __restrict__ b)
{
    int row  = blockIdx.x * 4 + (threadIdx.x >> 6);
    int lane = threadIdx.x & 63;
    const float4* r = (const float4*)(in + (size_t)row * N_EMBD);
    float4 v0 = r[lane];
    float4 v1 = r[lane + 64];
    float s  = (v0.x + v0.y) + (v0.z + v0.w) + (v1.x + v1.y) + (v1.z + v1.w);
    float ss = v0.x*v0.x + v0.y*v0.y + v0.z*v0.z + v0.w*v0.w
             + v1.x*v1.x + v1.y*v1.y + v1.z*v1.z + v1.w*v1.w;
    #pragma unroll
    for (int off = 32; off; off >>= 1) {
        s  += __shfl_xor(s, off);
        ss += __shfl_xor(ss, off);
    }
    float mu  = s * (1.0f / 512.0f);
    float var = ss * (1.0f / 512.0f) - mu * mu;
    float rs  = rsqrtf(var + 1e-5f);
    const float4* g4 = (const float4*)g;
    const float4* b4 = (const float4*)b;
    float4 G0 = g4[lane], G1 = g4[lane + 64];
    float4 B0 = b4[lane], B1 = b4[lane + 64];
    half4 h0, h1;
    h0[0] = (_Float16)((v0.x - mu) * rs * G0.x + B0.x);
    h0[1] = (_Float16)((v0.y - mu) * rs * G0.y + B0.y);
    h0[2] = (_Float16)((v0.z - mu) * rs * G0.z + B0.z);
    h0[3] = (_Float16)((v0.w - mu) * rs * G0.w + B0.w);
    h1[0] = (_Float16)((v1.x - mu) * rs * G1.x + B1.x);
    h1[1] = (_Float16)((v1.y - mu) * rs * G1.y + B1.y);
    h1[2] = (_Float16)((v1.z - mu) * rs * G1.z + B1.z);
    h1[3] = (_Float16)((v1.w - mu) * rs * G1.w + B1.w);
    half4* o = (half4*)(out + (size_t)row * N_EMBD);
    o[lane]      = h0;
    o[lane + 64] = h1;
}

// ---------------------------------------------------------------------------
// f16 MFMA GEMM (m97 structure): C[M][N] = A[M][K] @ Bt[N][K]^T
// ---------------------------------------------------------------------------
template<int OUTF16, int RELU>
__global__ __launch_bounds__(256) void gemm_mfma(
    const _Float16* __restrict__ A, const _Float16* __restrict__ Bt,
    const float* __restrict__ bias, const float* __restrict__ resid,
    void* __restrict__ Cv, int M, int N, int K, int ldB)
{
    __shared__ __attribute__((aligned(16))) _Float16 As[128 * 32];
    __shared__ __attribute__((aligned(16))) _Float16 Bs[128 * 32];
    const int tid  = threadIdx.x;
    const int wid  = tid >> 6;
    const int lane = tid & 63;
    const int row0 = blockIdx.y * 128;
    const int col0 = blockIdx.x * 128;
    const int wr   = (wid >> 1) * 64;
    const int wc   = (wid & 1) * 64;

    const int sA   = wid * 2;
    const int lrow = lane >> 2;
    const int lk   = (lane & 3) * 8;
    const _Float16* gA0 = A  + (size_t)(row0 + sA * 16 + lrow)       * K   + lk;
    const _Float16* gA1 = A  + (size_t)(row0 + (sA + 1) * 16 + lrow) * K   + lk;
    const _Float16* gB0 = Bt + (size_t)(col0 + sA * 16 + lrow)       * ldB + lk;
    const _Float16* gB1 = Bt + (size_t)(col0 + (sA + 1) * 16 + lrow) * ldB + lk;
    _Float16* lA0 = As + sA * 512;
    _Float16* lA1 = As + (sA + 1) * 512;
    _Float16* lB0 = Bs + sA * 512;
    _Float16* lB1 = Bs + (sA + 1) * 512;

    const _Float16* fA = As + (size_t)(wr + (lane & 15)) * 32 + (lane >> 4) * 8;
    const _Float16* fB = Bs + (size_t)(wc + (lane & 15)) * 32 + (lane >> 4) * 8;

    f32x4 acc[4][4] = {};

    for (int k0 = 0; k0 < K; k0 += 32) {
        GLOAD_LDS16(gA0 + k0, lA0);
        GLOAD_LDS16(gA1 + k0, lA1);
        GLOAD_LDS16(gB0 + k0, lB0);
        GLOAD_LDS16(gB1 + k0, lB1);
        __syncthreads();
        half8 af[4], bf[4];
        #pragma unroll
        for (int m = 0; m < 4; ++m) af[m] = *(const half8*)(fA + m * 16 * 32);
        #pragma unroll
        for (int n = 0; n < 4; ++n) bf[n] = *(const half8*)(fB + n * 16 * 32);
        #pragma unroll
        for (int m = 0; m < 4; ++m)
            #pragma unroll
            for (int n = 0; n < 4; ++n)
                acc[m][n] = __builtin_amdgcn_mfma_f32_16x16x32_f16(
                    af[m], bf[n], acc[m][n], 0, 0, 0);
        __syncthreads();
    }

    #pragma unroll
    for (int m = 0; m < 4; ++m) {
        #pragma unroll
        for (int n = 0; n < 4; ++n) {
            #pragma unroll
            for (int r = 0; r < 4; ++r) {
                int row = row0 + wr + m * 16 + (lane >> 4) * 4 + r;
                int col = col0 + wc + n * 16 + (lane & 15);
                float v = acc[m][n][r];
                if (bias) v += bias[col];
                if (RELU) v = fmaxf(v, 0.f);
                if (OUTF16) {
                    ((_Float16*)Cv)[(size_t)row * N + col] = (_Float16)v;
                } else {
                    if (resid) v += resid[(size_t)row * N + col];
                    ((float*)Cv)[(size_t)row * N + col] = v;
                }
            }
        }
    }
}

// ---------------------------------------------------------------------------
// MFMA flash-attention v2. One block per (batch, head, q-half of 128 rows);
// 4 waves x 32 q-rows. K staged [32][88]; V transposed [64][40] with
// conflict-free mapping; P via per-wave LDS [32][40].
// ---------------------------------------------------------------------------
template<int CAUSAL>
__global__ __launch_bounds__(256) void attn_mfma(
    const _Float16* __restrict__ Q, int ldq,
    const _Float16* __restrict__ Kg, const _Float16* __restrict__ Vg, int ldkv,
    const int* __restrict__ mask, const unsigned* __restrict__ flagp,
    _Float16* __restrict__ O)
{
    __shared__ __attribute__((aligned(16))) _Float16 Ks[32 * 88];
    __shared__ __attribute__((aligned(16))) _Float16 Vt[64 * 40];
    __shared__ __attribute__((aligned(16))) _Float16 Pl[4][32 * 40];

    const int qt   = blockIdx.x & 1;
    const int bh   = blockIdx.x >> 1;
    const int b    = bh >> 3;
    const int h    = bh & 7;
    const int tid  = threadIdx.x;
    const int wid  = tid >> 6;
    const int lane = tid & 63;
    const int l15  = lane & 15;
    const int kg8  = (lane >> 4) * 8;
    const int q0   = qt * 128 + wid * 32;
    const unsigned allones = flagp[0];
    const float scale = 0.04419417382415922f;   // 512^-0.5

    half8 af[2][2];
    #pragma unroll
    for (int m = 0; m < 2; ++m)
        #pragma unroll
        for (int c = 0; c < 2; ++c)
            af[m][c] = *(const half8*)(Q + (size_t)(b * TBLK + q0 + m * 16 + l15) * ldq
                                         + h * HEADD + c * 32 + kg8);

    f32x4 o[2][4] = {};
    float mrun[2][4], lrun[2][4];
    #pragma unroll
    for (int m = 0; m < 2; ++m)
        #pragma unroll
        for (int r = 0; r < 4; ++r) { mrun[m][r] = -1e30f; lrun[m][r] = 0.f; }

    _Float16* PlW = Pl[wid];
    const int kk = tid & 31;         // k row within tile
    const int dg = tid >> 5;         // 0..7 d-group of 8
    const _Float16* kgp = Kg + (size_t)(b * TBLK) * ldkv + h * HEADD;
    const _Float16* vgp = Vg + (size_t)(b * TBLK) * ldkv + h * HEADD;
    const int ktend = CAUSAL ? qt * 128 + 128 : TBLK;

    for (int kt = 0; kt < ktend; kt += 32) {
        __syncthreads();
        {
            half8 kv = *(const half8*)(kgp + (size_t)(kt + kk) * ldkv + dg * 8);
            half8 vv = *(const half8*)(vgp + (size_t)(kt + kk) * ldkv + dg * 8);
            *(half8*)&Ks[kk * 88 + dg * 8] = kv;
            #pragma unroll
            for (int j = 0; j < 8; ++j)
                Vt[(dg * 8 + j) * 40 + kk] = vv[j];
        }
        __syncthreads();
        if (!CAUSAL || kt < q0 + 32) {
            // S = Q @ K^T for this 32q x 32k tile
            f32x4 s[2][2] = {};
            #pragma unroll
            for (int c = 0; c < 2; ++c) {
                half8 bk0 = *(const half8*)&Ks[(l15)      * 88 + c * 32 + kg8];
                half8 bk1 = *(const half8*)&Ks[(16 + l15) * 88 + c * 32 + kg8];
                #pragma unroll
                for (int m = 0; m < 2; ++m) {
                    s[m][0] = __builtin_amdgcn_mfma_f32_16x16x32_f16(af[m][c], bk0, s[m][0], 0, 0, 0);
                    s[m][1] = __builtin_amdgcn_mfma_f32_16x16x32_f16(af[m][c], bk1, s[m][1], 0, 0, 0);
                }
            }
            #pragma unroll
            for (int m = 0; m < 2; ++m) {
                #pragma unroll
                for (int r = 0; r < 4; ++r) {
                    float s0 = s[m][0][r] * scale;
                    float s1 = s[m][1][r] * scale;
                    const int qrow = q0 + m * 16 + (lane >> 4) * 4 + r;
                    if (!allones) {
                        const int* mr = mask + (size_t)(b * TBLK + qrow) * TBLK + kt;
                        if (mr[l15] == 0)      s0 = -1e9f;
                        if (mr[16 + l15] == 0) s1 = -1e9f;
                    }
                    if (CAUSAL) {
                        if (kt + l15 > qrow)      s0 = -1e9f;
                        if (kt + 16 + l15 > qrow) s1 = -1e9f;
                    }
                    float tm = fmaxf(s0, s1);
                    tm = fmaxf(tm, __shfl_xor(tm, 1));
                    tm = fmaxf(tm, __shfl_xor(tm, 2));
                    tm = fmaxf(tm, __shfl_xor(tm, 4));
                    tm = fmaxf(tm, __shfl_xor(tm, 8));
                    float mnew = fmaxf(mrun[m][r], tm);
                    float fr = __expf(mrun[m][r] - mnew);
                    float p0 = __expf(s0 - mnew);
                    float p1 = __expf(s1 - mnew);
                    float rs = p0 + p1;
                    rs += __shfl_xor(rs, 1);
                    rs += __shfl_xor(rs, 2);
                    rs += __shfl_xor(rs, 4);
                    rs += __shfl_xor(rs, 8);
                    lrun[m][r] = lrun[m][r] * fr + rs;
                    mrun[m][r] = mnew;
                    o[m][0][r] *= fr; o[m][1][r] *= fr;
                    o[m][2][r] *= fr; o[m][3][r] *= fr;
                    _Float16* pw = PlW + (m * 16 + (lane >> 4) * 4 + r) * 40;
                    pw[l15]      = (_Float16)p0;
                    pw[16 + l15] = (_Float16)p1;
                }
            }
            half8 pa[2];
            #pragma unroll
            for (int m = 0; m < 2; ++m)
                pa[m] = *(const half8*)&PlW[(m * 16 + l15) * 40 + kg8];
            #pragma unroll
            for (int dn = 0; dn < 4; ++dn) {
                half8 bv = *(const half8*)&Vt[(dn * 16 + l15) * 40 + kg8];
                #pragma unroll
                for (int m = 0; m < 2; ++m)
                    o[m][dn] = __builtin_amdgcn_mfma_f32_16x16x32_f16(pa[m], bv, o[m][dn], 0, 0, 0);
            }
        }
    }

    #pragma unroll
    for (int m = 0; m < 2; ++m) {
        #pragma unroll
        for (int r = 0; r < 4; ++r) {
            float inv = 1.0f / lrun[m][r];
            const int qrow = q0 + m * 16 + (lane >> 4) * 4 + r;
            _Float16* op = O + (size_t)(b * TBLK + qrow) * N_EMBD + h * HEADD;
            #pragma unroll
            for (int dn = 0; dn < 4; ++dn)
                op[dn * 16 + l15] = (_Float16)(o[m][dn][r] * inv);
        }
    }
}

// ---------------------------------------------------------------------------
extern "C" void kernel_launch(void* const* d_in, const int* in_sizes, int n_in,
                              void* d_out, int out_size, void* d_ws, size_t ws_size,
                              hipStream_t stream) {
    const float* x    = (const float*)d_in[0];
    const float* ca   = (const float*)d_in[1];
    const int*   x_m  = (const int*)d_in[2];
    const int*   ca_m = (const int*)d_in[3];
    const float* Wq_s = (const float*)d_in[4];
    const float* Wk_s = (const float*)d_in[5];
    const float* Wv_s = (const float*)d_in[6];
    const float* Wo_s = (const float*)d_in[7];
    const float* bo_s = (const float*)d_in[8];
    const float* Wq_c = (const float*)d_in[9];
    const float* Wk_c = (const float*)d_in[10];
    const float* Wv_c = (const float*)d_in[11];
    const float* Wo_c = (const float*)d_in[12];
    const float* bo_c = (const float*)d_in[13];
    const float* g1   = (const float*)d_in[14];
    const float* be1  = (const float*)d_in[15];
    const float* g2   = (const float*)d_in[16];
    const float* be2  = (const float*)d_in[17];
    const float* g3   = (const float*)d_in[18];
    const float* be3  = (const float*)d_in[19];
    const float* Wf1  = (const float*)d_in[20];
    const float* bf1  = (const float*)d_in[21];
    const float* Wf2  = (const float*)d_in[22];
    const float* bf2  = (const float*)d_in[23];

    float* out = (float*)d_out;
    char*  ws  = (char*)d_ws;

    const size_t MiB = 1024 * 1024;
    if (ws_size < 90 * MiB) return;

    _Float16* LNh  = (_Float16*)(ws);             // 16 MiB; also ATT out
    _Float16* QKV  = (_Float16*)(ws + 16 * MiB);  // [16384][1536] 48 MiB (16..64)
    _Float16* Qc   = (_Float16*)(ws + 16 * MiB);  // [16384][512]  (cross phase)
    _Float16* KVc  = (_Float16*)(ws + 32 * MiB);  // [16384][1024] (cross phase)
    _Float16* FFC  = (_Float16*)(ws + 16 * MiB);  // [16384][2048] 64 MiB (FF phase)
    _Float16* cah  = (_Float16*)(ws + 64 * MiB);  // 16 MiB
    _Float16* wqkv_s = (_Float16*)(ws + 80 * MiB);      // [1536][512]
    _Float16* wos    = wqkv_s + 1536 * 512;             // [512][512]
    _Float16* wqc    = wos    + 512 * 512;              // [512][512]
    _Float16* wkv_c  = wqc    + 512 * 512;              // [1024][512]
    _Float16* woc    = wkv_c  + 1024 * 512;             // [512][512]
    _Float16* wf1t   = woc    + 512 * 512;              // [2048][512]
    _Float16* wf2t   = wf1t   + 2048 * 512;             // [512][2048]
    unsigned* flags  = (unsigned*)(ws + 89 * MiB);      // [0]=x_m, [1]=ca_m

    dim3 blk(256);
    dim3 g5(16, 16);
    flag_init<<<1, 64, 0, stream>>>(flags);
    mask_check<<<1024, blk, 0, stream>>>(x_m,  MROWS * TBLK, flags);
    mask_check<<<1024, blk, 0, stream>>>(ca_m, MROWS * TBLK, flags + 1);

    wtrans<<<g5, blk, 0, stream>>>(Wq_s, wqkv_s,              N_EMBD, N_EMBD);
    wtrans<<<g5, blk, 0, stream>>>(Wk_s, wqkv_s + 512 * 512,  N_EMBD, N_EMBD);
    wtrans<<<g5, blk, 0, stream>>>(Wv_s, wqkv_s + 1024 * 512, N_EMBD, N_EMBD);
    wtrans<<<g5, blk, 0, stream>>>(Wo_s, wos, N_EMBD, N_EMBD);
    wtrans<<<g5, blk, 0, stream>>>(Wq_c, wqc, N_EMBD, N_EMBD);
    wtrans<<<g5, blk, 0, stream>>>(Wk_c, wkv_c,             N_EMBD, N_EMBD);
    wtrans<<<g5, blk, 0, stream>>>(Wv_c, wkv_c + 512 * 512, N_EMBD, N_EMBD);
    wtrans<<<g5, blk, 0, stream>>>(Wo_c, woc, N_EMBD, N_EMBD);
    wtrans<<<dim3(FF_DIM / 32, N_EMBD / 32), blk, 0, stream>>>(Wf1, wf1t, N_EMBD, FF_DIM);
    wtrans<<<dim3(N_EMBD / 32, FF_DIM / 32), blk, 0, stream>>>(Wf2, wf2t, FF_DIM, N_EMBD);
    conv_f16<<<2048, blk, 0, stream>>>(ca, cah, MROWS * N_EMBD / 4);

    dim3 gp(N_EMBD / 128, MROWS / 128);    // (4, 128)
    dim3 gqkv(1536 / 128, MROWS / 128);    // (12, 128)
    dim3 gkv(1024 / 128, MROWS / 128);     // (8, 128)
    dim3 gf1(FF_DIM / 128, MROWS / 128);   // (16, 128)
    dim3 ga(BATCH * NHEADS * 2);

    // --- self-attention: out = x + Attn(LN1(x)) @ Wo + bo ---
    ln_kernel<<<MROWS / 4, blk, 0, stream>>>(x, LNh, g1, be1);
    gemm_mfma<1,0><<<gqkv, blk, 0, stream>>>(LNh, wqkv_s, nullptr, nullptr, QKV, MROWS, 1536, N_EMBD, N_EMBD);
    attn_mfma<1><<<ga, blk, 0, stream>>>(QKV, 1536, QKV + 512, QKV + 1024, 1536, x_m, flags, LNh);
    gemm_mfma<0,0><<<gp, blk, 0, stream>>>(LNh, wos, bo_s, x, out, MROWS, N_EMBD, N_EMBD, N_EMBD);

    // --- cross-attention: out = out + Attn(LN2(out), ca) @ Wo + bo ---
    ln_kernel<<<MROWS / 4, blk, 0, stream>>>(out, LNh, g2, be2);
    gemm_mfma<1,0><<<gp, blk, 0, stream>>>(LNh, wqc, nullptr, nullptr, Qc, MROWS, N_EMBD, N_EMBD, N_EMBD);
    gemm_mfma<1,0><<<gkv, blk, 0, stream>>>(cah, wkv_c, nullptr, nullptr, KVc, MROWS, 1024, N_EMBD, N_EMBD);
    attn_mfma<0><<<ga, blk, 0, stream>>>(Qc, 512, KVc, KVc + 512, 1024, ca_m, flags + 1, LNh);
    gemm_mfma<0,0><<<gp, blk, 0, stream>>>(LNh, woc, bo_c, out, out, MROWS, N_EMBD, N_EMBD, N_EMBD);

    // --- FFN: out = out + relu(LN3(out)@Wf1+bf1)@Wf2+bf2 ---
    ln_kernel<<<MROWS / 4, blk, 0, stream>>>(out, LNh, g3, be3);
    gemm_mfma<1,1><<<gf1, blk, 0, stream>>>(LNh, wf1t, bf1, nullptr, FFC, MROWS, FF_DIM, N_EMBD, N_EMBD);
    gemm_mfma<0,0><<<gp, blk, 0, stream>>>(FFC, wf2t, bf2, out, out, MROWS, N_EMBD, FF_DIM, FF_DIM);
}

// Round 6
// 686.690 us; speedup vs baseline: 3.6703x; 1.0445x over previous
//
#include <hip/hip_runtime.h>
#include <hip/hip_bf16.h>
#include <cstddef>

#define N_EMBD 512
#define NHEADS 8
#define HEADD  64
#define TBLK   256
#define BATCH  64
#define FF_DIM 2048
#define MROWS  (BATCH * TBLK)   // 16384

typedef _Float16 half8 __attribute__((ext_vector_type(8)));
typedef _Float16 half4 __attribute__((ext_vector_type(4)));
typedef float    f32x4 __attribute__((ext_vector_type(4)));

#define GLOAD_LDS16(g, l) __builtin_amdgcn_global_load_lds( \
    (const __attribute__((address_space(1))) void*)(g),     \
    (__attribute__((address_space(3))) void*)(l), 16, 0, 0)

// ---------------------------------------------------------------------------
// f32 -> f16 elementwise convert (for ca)
// ---------------------------------------------------------------------------
__global__ __launch_bounds__(256) void conv_f16(
    const float* __restrict__ in, _Float16* __restrict__ out, int n4)
{
    int i = blockIdx.x * 256 + threadIdx.x;
    int stride = gridDim.x * 256;
    for (; i < n4; i += stride) {
        float4 v = ((const float4*)in)[i];
        half4 h;
        h[0] = (_Float16)v.x; h[1] = (_Float16)v.y;
        h[2] = (_Float16)v.z; h[3] = (_Float16)v.w;
        ((half4*)out)[i] = h;
    }
}

// ---------------------------------------------------------------------------
// mask flag: flag stays nonzero iff ALL mask entries are nonzero.
// ---------------------------------------------------------------------------
__global__ void flag_init(unsigned* f) {
    if (threadIdx.x < 2) f[threadIdx.x] = 0xFFFFFFFFu;
}
__global__ __launch_bounds__(256) void mask_check(
    const int* __restrict__ m, int n, unsigned* __restrict__ flag)
{
    int i = blockIdx.x * 256 + threadIdx.x;
    const int stride = gridDim.x * 256;
    bool ok = true;
    for (; i < n; i += stride) ok = ok && (m[i] != 0);
    if (!__all(ok)) {
        if ((threadIdx.x & 63) == 0) atomicAnd(flag, 0u);
    }
}

// ---------------------------------------------------------------------------
// Weight transpose + convert: W[K][N] f32 -> Wt[N][K] f16. 32x32 LDS tiles.
// ---------------------------------------------------------------------------
__global__ __launch_bounds__(256) void wtrans(
    const float* __restrict__ W, _Float16* __restrict__ Wt, int K, int N)
{
    __shared__ float t[32][33];
    const int n0 = blockIdx.x * 32;
    const int k0 = blockIdx.y * 32;
    const int cx = threadIdx.x & 31;
    const int ry = threadIdx.x >> 5;   // 0..7
    #pragma unroll
    for (int i = 0; i < 4; ++i)
        t[ry + i * 8][cx] = W[(size_t)(k0 + ry + i * 8) * N + n0 + cx];
    __syncthreads();
    #pragma unroll
    for (int i = 0; i < 4; ++i)
        Wt[(size_t)(n0 + ry + i * 8) * K + k0 + cx] = (_Float16)t[cx][ry + i * 8];
}

// ---------------------------------------------------------------------------
// LayerNorm: one wave per row of 512; writes f16.
// ---------------------------------------------------------------------------
__global__ __launch_bounds__(256) void ln_kernel(
    const float* __restrict__ in, _Float16* __restrict__ out,
    const float* __restrict__ g, const float* __restrict__ b)
{
    int row  = blockIdx.x * 4 + (threadIdx.x >> 6);
    int lane = threadIdx.x & 63;
    const float4* r = (const float4*)(in + (size_t)row * N_EMBD);
    float4 v0 = r[lane];
    float4 v1 = r[lane + 64];
    float s  = (v0.x + v0.y) + (v0.z + v0.w) + (v1.x + v1.y) + (v1.z + v1.w);
    float ss = v0.x*v0.x + v0.y*v0.y + v0.z*v0.z + v0.w*v0.w
             + v1.x*v1.x + v1.y*v1.y + v1.z*v1.z + v1.w*v1.w;
    #pragma unroll
    for (int off = 32; off; off >>= 1) {
        s  += __shfl_xor(s, off);
        ss += __shfl_xor(ss, off);
    }
    float mu  = s * (1.0f / 512.0f);
    float var = ss * (1.0f / 512.0f) - mu * mu;
    float rs  = rsqrtf(var + 1e-5f);
    const float4* g4 = (const float4*)g;
    const float4* b4 = (const float4*)b;
    float4 G0 = g4[lane], G1 = g4[lane + 64];
    float4 B0 = b4[lane], B1 = b4[lane + 64];
    half4 h0, h1;
    h0[0] = (_Float16)((v0.x - mu) * rs * G0.x + B0.x);
    h0[1] = (_Float16)((v0.y - mu) * rs * G0.y + B0.y);
    h0[2] = (_Float16)((v0.z - mu) * rs * G0.z + B0.z);
    h0[3] = (_Float16)((v0.w - mu) * rs * G0.w + B0.w);
    h1[0] = (_Float16)((v1.x - mu) * rs * G1.x + B1.x);
    h1[1] = (_Float16)((v1.y - mu) * rs * G1.y + B1.y);
    h1[2] = (_Float16)((v1.z - mu) * rs * G1.z + B1.z);
    h1[3] = (_Float16)((v1.w - mu) * rs * G1.w + B1.w);
    half4* o = (half4*)(out + (size_t)row * N_EMBD);
    o[lane]      = h0;
    o[lane + 64] = h1;
}

// ---------------------------------------------------------------------------
// f16 MFMA GEMM: C[M][N] = A[M][K] @ Bt[N][K]^T
// + bijective chunked XCD swizzle (T1): XCD k owns a contiguous tile range,
//   so tiles sharing a 128-row A-panel hit the same per-XCD L2.
// + LDS chunk XOR-swizzle (T2, both-sides): LDS dest stays linear
//   (global_load_lds), per-lane GLOBAL source chunk and frag-read chunk are
//   permuted by swz(row) = (row&3)^((row>>2)&3) -> frag reads 2-way (free).
// ---------------------------------------------------------------------------
template<int OUTF16, int RELU>
__global__ __launch_bounds__(256) void gemm_mfma(
    const _Float16* __restrict__ A, const _Float16* __restrict__ Bt,
    const float* __restrict__ bias, const float* __restrict__ resid,
    void* __restrict__ Cv, int M, int N, int K, int ldB)
{
    __shared__ __attribute__((aligned(16))) _Float16 As[128 * 32];
    __shared__ __attribute__((aligned(16))) _Float16 Bs[128 * 32];
    const int tid  = threadIdx.x;
    const int wid  = tid >> 6;
    const int lane = tid & 63;

    // chunked XCD swizzle (grids here always have nwg % 8 == 0)
    const int nx   = gridDim.x;
    const int nwg  = nx * gridDim.y;
    const int flat = blockIdx.y * nx + blockIdx.x;
    const int swzb = (flat & 7) * (nwg >> 3) + (flat >> 3);
    const int col0 = (swzb % nx) * 128;
    const int row0 = (swzb / nx) * 128;

    const int wr   = (wid >> 1) * 64;
    const int wc   = (wid & 1) * 64;

    // staging: 8 segments of 1KB per matrix; wave w owns segments 2w, 2w+1.
    // LDS dest linear: seg*1024 + lane*16  <=> (row = s*16 + lane/4, chunk = lane&3)
    // source chunk permuted so LDS (row,chunk) holds logical chunk^swz(row):
    //   chunk_logical = (lane&3) ^ ((lane>>2)&3) ^ (lane>>4)   [s*4 ≡ 0 mod 4]
    const int sA    = wid * 2;
    const int lrow  = lane >> 2;
    const int lkswz = ((lane & 3) ^ ((lane >> 2) & 3) ^ (lane >> 4)) * 8;
    const _Float16* gA0 = A  + (size_t)(row0 + sA * 16 + lrow)       * K   + lkswz;
    const _Float16* gA1 = A  + (size_t)(row0 + (sA + 1) * 16 + lrow) * K   + lkswz;
    const _Float16* gB0 = Bt + (size_t)(col0 + sA * 16 + lrow)       * ldB + lkswz;
    const _Float16* gB1 = Bt + (size_t)(col0 + (sA + 1) * 16 + lrow) * ldB + lkswz;
    _Float16* lA0 = As + sA * 512;
    _Float16* lA1 = As + (sA + 1) * 512;
    _Float16* lB0 = Bs + sA * 512;
    _Float16* lB1 = Bs + (sA + 1) * 512;

    // fragment read: logical chunk g = lane>>4 stored at chunk g^swz(row);
    // frag rows = base + l15 with base%16==0 -> swz = (l15&3)^((l15>>2)&3)
    const int l15  = lane & 15;
    const int swzr = (l15 & 3) ^ ((l15 >> 2) & 3);
    const int gidx = ((lane >> 4) ^ swzr) * 8;
    const _Float16* fA = As + (size_t)(wr + l15) * 32 + gidx;
    const _Float16* fB = Bs + (size_t)(wc + l15) * 32 + gidx;

    f32x4 acc[4][4] = {};

    for (int k0 = 0; k0 < K; k0 += 32) {
        GLOAD_LDS16(gA0 + k0, lA0);
        GLOAD_LDS16(gA1 + k0, lA1);
        GLOAD_LDS16(gB0 + k0, lB0);
        GLOAD_LDS16(gB1 + k0, lB1);
        __syncthreads();
        half8 af[4], bf[4];
        #pragma unroll
        for (int m = 0; m < 4; ++m) af[m] = *(const half8*)(fA + m * 16 * 32);
        #pragma unroll
        for (int n = 0; n < 4; ++n) bf[n] = *(const half8*)(fB + n * 16 * 32);
        #pragma unroll
        for (int m = 0; m < 4; ++m)
            #pragma unroll
            for (int n = 0; n < 4; ++n)
                acc[m][n] = __builtin_amdgcn_mfma_f32_16x16x32_f16(
                    af[m], bf[n], acc[m][n], 0, 0, 0);
        __syncthreads();
    }

    #pragma unroll
    for (int m = 0; m < 4; ++m) {
        #pragma unroll
        for (int n = 0; n < 4; ++n) {
            #pragma unroll
            for (int r = 0; r < 4; ++r) {
                int row = row0 + wr + m * 16 + (lane >> 4) * 4 + r;
                int col = col0 + wc + n * 16 + l15;
                float v = acc[m][n][r];
                if (bias) v += bias[col];
                if (RELU) v = fmaxf(v, 0.f);
                if (OUTF16) {
                    ((_Float16*)Cv)[(size_t)row * N + col] = (_Float16)v;
                } else {
                    if (resid) v += resid[(size_t)row * N + col];
                    ((float*)Cv)[(size_t)row * N + col] = v;
                }
            }
        }
    }
}

// ---------------------------------------------------------------------------
// MFMA flash-attention v2. One block per (batch, head, q-half of 128 rows);
// 4 waves x 32 q-rows. K staged [32][88]; V transposed [64][40] with
// conflict-free mapping; P via per-wave LDS [32][40].
// ---------------------------------------------------------------------------
template<int CAUSAL>
__global__ __launch_bounds__(256) void attn_mfma(
    const _Float16* __restrict__ Q, int ldq,
    const _Float16* __restrict__ Kg, const _Float16* __restrict__ Vg, int ldkv,
    const int* __restrict__ mask, const unsigned* __restrict__ flagp,
    _Float16* __restrict__ O)
{
    __shared__ __attribute__((aligned(16))) _Float16 Ks[32 * 88];
    __shared__ __attribute__((aligned(16))) _Float16 Vt[64 * 40];
    __shared__ __attribute__((aligned(16))) _Float16 Pl[4][32 * 40];

    const int qt   = blockIdx.x & 1;
    const int bh   = blockIdx.x >> 1;
    const int b    = bh >> 3;
    const int h    = bh & 7;
    const int tid  = threadIdx.x;
    const int wid  = tid >> 6;
    const int lane = tid & 63;
    const int l15  = lane & 15;
    const int kg8  = (lane >> 4) * 8;
    const int q0   = qt * 128 + wid * 32;
    const unsigned allones = flagp[0];
    const float scale = 0.04419417382415922f;   // 512^-0.5

    half8 af[2][2];
    #pragma unroll
    for (int m = 0; m < 2; ++m)
        #pragma unroll
        for (int c = 0; c < 2; ++c)
            af[m][c] = *(const half8*)(Q + (size_t)(b * TBLK + q0 + m * 16 + l15) * ldq
                                         + h * HEADD + c * 32 + kg8);

    f32x4 o[2][4] = {};
    float mrun[2][4], lrun[2][4];
    #pragma unroll
    for (int m = 0; m < 2; ++m)
        #pragma unroll
        for (int r = 0; r < 4; ++r) { mrun[m][r] = -1e30f; lrun[m][r] = 0.f; }

    _Float16* PlW = Pl[wid];
    const int kk = tid & 31;         // k row within tile
    const int dg = tid >> 5;         // 0..7 d-group of 8
    const _Float16* kgp = Kg + (size_t)(b * TBLK) * ldkv + h * HEADD;
    const _Float16* vgp = Vg + (size_t)(b * TBLK) * ldkv + h * HEADD;
    const int ktend = CAUSAL ? qt * 128 + 128 : TBLK;

    for (int kt = 0; kt < ktend; kt += 32) {
        __syncthreads();
        {
            half8 kv = *(const half8*)(kgp + (size_t)(kt + kk) * ldkv + dg * 8);
            half8 vv = *(const half8*)(vgp + (size_t)(kt + kk) * ldkv + dg * 8);
            *(half8*)&Ks[kk * 88 + dg * 8] = kv;
            #pragma unroll
            for (int j = 0; j < 8; ++j)
                Vt[(dg * 8 + j) * 40 + kk] = vv[j];
        }
        __syncthreads();
        if (!CAUSAL || kt < q0 + 32) {
            // S = Q @ K^T for this 32q x 32k tile
            f32x4 s[2][2] = {};
            #pragma unroll
            for (int c = 0; c < 2; ++c) {
                half8 bk0 = *(const half8*)&Ks[(l15)      * 88 + c * 32 + kg8];
                half8 bk1 = *(const half8*)&Ks[(16 + l15) * 88 + c * 32 + kg8];
                #pragma unroll
                for (int m = 0; m < 2; ++m) {
                    s[m][0] = __builtin_amdgcn_mfma_f32_16x16x32_f16(af[m][c], bk0, s[m][0], 0, 0, 0);
                    s[m][1] = __builtin_amdgcn_mfma_f32_16x16x32_f16(af[m][c], bk1, s[m][1], 0, 0, 0);
                }
            }
            #pragma unroll
            for (int m = 0; m < 2; ++m) {
                #pragma unroll
                for (int r = 0; r < 4; ++r) {
                    float s0 = s[m][0][r] * scale;
                    float s1 = s[m][1][r] * scale;
                    const int qrow = q0 + m * 16 + (lane >> 4) * 4 + r;
                    if (!allones) {
                        const int* mr = mask + (size_t)(b * TBLK + qrow) * TBLK + kt;
                        if (mr[l15] == 0)      s0 = -1e9f;
                        if (mr[16 + l15] == 0) s1 = -1e9f;
                    }
                    if (CAUSAL) {
                        if (kt + l15 > qrow)      s0 = -1e9f;
                        if (kt + 16 + l15 > qrow) s1 = -1e9f;
                    }
                    float tm = fmaxf(s0, s1);
                    tm = fmaxf(tm, __shfl_xor(tm, 1));
                    tm = fmaxf(tm, __shfl_xor(tm, 2));
                    tm = fmaxf(tm, __shfl_xor(tm, 4));
                    tm = fmaxf(tm, __shfl_xor(tm, 8));
                    float mnew = fmaxf(mrun[m][r], tm);
                    float fr = __expf(mrun[m][r] - mnew);
                    float p0 = __expf(s0 - mnew);
                    float p1 = __expf(s1 - mnew);
                    float rs = p0 + p1;
                    rs += __shfl_xor(rs, 1);
                    rs += __shfl_xor(rs, 2);
                    rs += __shfl_xor(rs, 4);
                    rs += __shfl_xor(rs, 8);
                    lrun[m][r] = lrun[m][r] * fr + rs;
                    mrun[m][r] = mnew;
                    o[m][0][r] *= fr; o[m][1][r] *= fr;
                    o[m][2][r] *= fr; o[m][3][r] *= fr;
                    _Float16* pw = PlW + (m * 16 + (lane >> 4) * 4 + r) * 40;
                    pw[l15]      = (_Float16)p0;
                    pw[16 + l15] = (_Float16)p1;
                }
            }
            half8 pa[2];
            #pragma unroll
            for (int m = 0; m < 2; ++m)
                pa[m] = *(const half8*)&PlW[(m * 16 + l15) * 40 + kg8];
            #pragma unroll
            for (int dn = 0; dn < 4; ++dn) {
                half8 bv = *(const half8*)&Vt[(dn * 16 + l15) * 40 + kg8];
                #pragma unroll
                for (int m = 0; m < 2; ++m)
                    o[m][dn] = __builtin_amdgcn_mfma_f32_16x16x32_f16(pa[m], bv, o[m][dn], 0, 0, 0);
            }
        }
    }

    #pragma unroll
    for (int m = 0; m < 2; ++m) {
        #pragma unroll
        for (int r = 0; r < 4; ++r) {
            float inv = 1.0f / lrun[m][r];
            const int qrow = q0 + m * 16 + (lane >> 4) * 4 + r;
            _Float16* op = O + (size_t)(b * TBLK + qrow) * N_EMBD + h * HEADD;
            #pragma unroll
            for (int dn = 0; dn < 4; ++dn)
                op[dn * 16 + l15] = (_Float16)(o[m][dn][r] * inv);
        }
    }
}

// ---------------------------------------------------------------------------
extern "C" void kernel_launch(void* const* d_in, const int* in_sizes, int n_in,
                              void* d_out, int out_size, void* d_ws, size_t ws_size,
                              hipStream_t stream) {
    const float* x    = (const float*)d_in[0];
    const float* ca   = (const float*)d_in[1];
    const int*   x_m  = (const int*)d_in[2];
    const int*   ca_m = (const int*)d_in[3];
    const float* Wq_s = (const float*)d_in[4];
    const float* Wk_s = (const float*)d_in[5];
    const float* Wv_s = (const float*)d_in[6];
    const float* Wo_s = (const float*)d_in[7];
    const float* bo_s = (const float*)d_in[8];
    const float* Wq_c = (const float*)d_in[9];
    const float* Wk_c = (const float*)d_in[10];
    const float* Wv_c = (const float*)d_in[11];
    const float* Wo_c = (const float*)d_in[12];
    const float* bo_c = (const float*)d_in[13];
    const float* g1   = (const float*)d_in[14];
    const float* be1  = (const float*)d_in[15];
    const float* g2   = (const float*)d_in[16];
    const float* be2  = (const float*)d_in[17];
    const float* g3   = (const float*)d_in[18];
    const float* be3  = (const float*)d_in[19];
    const float* Wf1  = (const float*)d_in[20];
    const float* bf1  = (const float*)d_in[21];
    const float* Wf2  = (const float*)d_in[22];
    const float* bf2  = (const float*)d_in[23];

    float* out = (float*)d_out;
    char*  ws  = (char*)d_ws;

    const size_t MiB = 1024 * 1024;
    if (ws_size < 90 * MiB) return;

    _Float16* LNh  = (_Float16*)(ws);             // 16 MiB; also ATT out
    _Float16* QKV  = (_Float16*)(ws + 16 * MiB);  // [16384][1536] 48 MiB (16..64)
    _Float16* Qc   = (_Float16*)(ws + 16 * MiB);  // [16384][512]  (cross phase)
    _Float16* KVc  = (_Float16*)(ws + 32 * MiB);  // [16384][1024] (cross phase)
    _Float16* FFC  = (_Float16*)(ws + 16 * MiB);  // [16384][2048] 64 MiB (FF phase)
    _Float16* cah  = (_Float16*)(ws + 64 * MiB);  // 16 MiB
    _Float16* wqkv_s = (_Float16*)(ws + 80 * MiB);      // [1536][512]
    _Float16* wos    = wqkv_s + 1536 * 512;             // [512][512]
    _Float16* wqc    = wos    + 512 * 512;              // [512][512]
    _Float16* wkv_c  = wqc    + 512 * 512;              // [1024][512]
    _Float16* woc    = wkv_c  + 1024 * 512;             // [512][512]
    _Float16* wf1t   = woc    + 512 * 512;              // [2048][512]
    _Float16* wf2t   = wf1t   + 2048 * 512;             // [512][2048]
    unsigned* flags  = (unsigned*)(ws + 89 * MiB);      // [0]=x_m, [1]=ca_m

    dim3 blk(256);
    dim3 g5(16, 16);
    flag_init<<<1, 64, 0, stream>>>(flags);
    mask_check<<<1024, blk, 0, stream>>>(x_m,  MROWS * TBLK, flags);
    mask_check<<<1024, blk, 0, stream>>>(ca_m, MROWS * TBLK, flags + 1);

    wtrans<<<g5, blk, 0, stream>>>(Wq_s, wqkv_s,              N_EMBD, N_EMBD);
    wtrans<<<g5, blk, 0, stream>>>(Wk_s, wqkv_s + 512 * 512,  N_EMBD, N_EMBD);
    wtrans<<<g5, blk, 0, stream>>>(Wv_s, wqkv_s + 1024 * 512, N_EMBD, N_EMBD);
    wtrans<<<g5, blk, 0, stream>>>(Wo_s, wos, N_EMBD, N_EMBD);
    wtrans<<<g5, blk, 0, stream>>>(Wq_c, wqc, N_EMBD, N_EMBD);
    wtrans<<<g5, blk, 0, stream>>>(Wk_c, wkv_c,             N_EMBD, N_EMBD);
    wtrans<<<g5, blk, 0, stream>>>(Wv_c, wkv_c + 512 * 512, N_EMBD, N_EMBD);
    wtrans<<<g5, blk, 0, stream>>>(Wo_c, woc, N_EMBD, N_EMBD);
    wtrans<<<dim3(FF_DIM / 32, N_EMBD / 32), blk, 0, stream>>>(Wf1, wf1t, N_EMBD, FF_DIM);
    wtrans<<<dim3(N_EMBD / 32, FF_DIM / 32), blk, 0, stream>>>(Wf2, wf2t, FF_DIM, N_EMBD);
    conv_f16<<<2048, blk, 0, stream>>>(ca, cah, MROWS * N_EMBD / 4);

    dim3 gp(N_EMBD / 128, MROWS / 128);    // (4, 128)
    dim3 gqkv(1536 / 128, MROWS / 128);    // (12, 128)
    dim3 gkv(1024 / 128, MROWS / 128);     // (8, 128)
    dim3 gf1(FF_DIM / 128, MROWS / 128);   // (16, 128)
    dim3 ga(BATCH * NHEADS * 2);

    // --- self-attention: out = x + Attn(LN1(x)) @ Wo + bo ---
    ln_kernel<<<MROWS / 4, blk, 0, stream>>>(x, LNh, g1, be1);
    gemm_mfma<1,0><<<gqkv, blk, 0, stream>>>(LNh, wqkv_s, nullptr, nullptr, QKV, MROWS, 1536, N_EMBD, N_EMBD);
    attn_mfma<1><<<ga, blk, 0, stream>>>(QKV, 1536, QKV + 512, QKV + 1024, 1536, x_m, flags, LNh);
    gemm_mfma<0,0><<<gp, blk, 0, stream>>>(LNh, wos, bo_s, x, out, MROWS, N_EMBD, N_EMBD, N_EMBD);

    // --- cross-attention: out = out + Attn(LN2(out), ca) @ Wo + bo ---
    ln_kernel<<<MROWS / 4, blk, 0, stream>>>(out, LNh, g2, be2);
    gemm_mfma<1,0><<<gp, blk, 0, stream>>>(LNh, wqc, nullptr, nullptr, Qc, MROWS, N_EMBD, N_EMBD, N_EMBD);
    gemm_mfma<1,0><<<gkv, blk, 0, stream>>>(cah, wkv_c, nullptr, nullptr, KVc, MROWS, 1024, N_EMBD, N_EMBD);
    attn_mfma<0><<<ga, blk, 0, stream>>>(Qc, 512, KVc, KVc + 512, 1024, ca_m, flags + 1, LNh);
    gemm_mfma<0,0><<<gp, blk, 0, stream>>>(LNh, woc, bo_c, out, out, MROWS, N_EMBD, N_EMBD, N_EMBD);

    // --- FFN: out = out + relu(LN3(out)@Wf1+bf1)@Wf2+bf2 ---
    ln_kernel<<<MROWS / 4, blk, 0, stream>>>(out, LNh, g3, be3);
    gemm_mfma<1,1><<<gf1, blk, 0, stream>>>(LNh, wf1t, bf1, nullptr, FFC, MROWS, FF_DIM, N_EMBD, N_EMBD);
    gemm_mfma<0,0><<<gp, blk, 0, stream>>>(FFC, wf2t, bf2, out, out, MROWS, N_EMBD, FF_DIM, FF_DIM);
}

// Round 8
// 616.294 us; speedup vs baseline: 4.0895x; 1.1142x over previous
//
#include <hip/hip_runtime.h>
#include <hip/hip_bf16.h>
#include <cstddef>

#define N_EMBD 512
#define NHEADS 8
#define HEADD  64
#define TBLK   256
#define BATCH  64
#define FF_DIM 2048
#define MROWS  (BATCH * TBLK)   // 16384

typedef _Float16 half8 __attribute__((ext_vector_type(8)));
typedef _Float16 half4 __attribute__((ext_vector_type(4)));
typedef float    f32x4 __attribute__((ext_vector_type(4)));

#define GLOAD_LDS16(g, l) __builtin_amdgcn_global_load_lds( \
    (const __attribute__((address_space(1))) void*)(g),     \
    (__attribute__((address_space(3))) void*)(l), 16, 0, 0)

// ---------------------------------------------------------------------------
// f32 -> f16 elementwise convert (for ca)
// ---------------------------------------------------------------------------
__global__ __launch_bounds__(256) void conv_f16(
    const float* __restrict__ in, _Float16* __restrict__ out, int n4)
{
    int i = blockIdx.x * 256 + threadIdx.x;
    int stride = gridDim.x * 256;
    for (; i < n4; i += stride) {
        float4 v = ((const float4*)in)[i];
        half4 h;
        h[0] = (_Float16)v.x; h[1] = (_Float16)v.y;
        h[2] = (_Float16)v.z; h[3] = (_Float16)v.w;
        ((half4*)out)[i] = h;
    }
}

// ---------------------------------------------------------------------------
// mask flag: flag stays nonzero iff ALL mask entries are nonzero.
// ---------------------------------------------------------------------------
__global__ void flag_init(unsigned* f) {
    if (threadIdx.x < 2) f[threadIdx.x] = 0xFFFFFFFFu;
}
__global__ __launch_bounds__(256) void mask_check(
    const int* __restrict__ m, int n, unsigned* __restrict__ flag)
{
    int i = blockIdx.x * 256 + threadIdx.x;
    const int stride = gridDim.x * 256;
    bool ok = true;
    for (; i < n; i += stride) ok = ok && (m[i] != 0);
    if (!__all(ok)) {
        if ((threadIdx.x & 63) == 0) atomicAnd(flag, 0u);
    }
}

// ---------------------------------------------------------------------------
// Weight transpose + convert: W[K][N] f32 -> Wt[N][K] f16. 32x32 LDS tiles.
// ---------------------------------------------------------------------------
__global__ __launch_bounds__(256) void wtrans(
    const float* __restrict__ W, _Float16* __restrict__ Wt, int K, int N)
{
    __shared__ float t[32][33];
    const int n0 = blockIdx.x * 32;
    const int k0 = blockIdx.y * 32;
    const int cx = threadIdx.x & 31;
    const int ry = threadIdx.x >> 5;   // 0..7
    #pragma unroll
    for (int i = 0; i < 4; ++i)
        t[ry + i * 8][cx] = W[(size_t)(k0 + ry + i * 8) * N + n0 + cx];
    __syncthreads();
    #pragma unroll
    for (int i = 0; i < 4; ++i)
        Wt[(size_t)(n0 + ry + i * 8) * K + k0 + cx] = (_Float16)t[cx][ry + i * 8];
}

// ---------------------------------------------------------------------------
// LayerNorm: one wave per row of 512; writes f16.
// ---------------------------------------------------------------------------
__global__ __launch_bounds__(256) void ln_kernel(
    const float* __restrict__ in, _Float16* __restrict__ out,
    const float* __restrict__ g, const float* __restrict__ b)
{
    int row  = blockIdx.x * 4 + (threadIdx.x >> 6);
    int lane = threadIdx.x & 63;
    const float4* r = (const float4*)(in + (size_t)row * N_EMBD);
    float4 v0 = r[lane];
    float4 v1 = r[lane + 64];
    float s  = (v0.x + v0.y) + (v0.z + v0.w) + (v1.x + v1.y) + (v1.z + v1.w);
    float ss = v0.x*v0.x + v0.y*v0.y + v0.z*v0.z + v0.w*v0.w
             + v1.x*v1.x + v1.y*v1.y + v1.z*v1.z + v1.w*v1.w;
    #pragma unroll
    for (int off = 32; off; off >>= 1) {
        s  += __shfl_xor(s, off);
        ss += __shfl_xor(ss, off);
    }
    float mu  = s * (1.0f / 512.0f);
    float var = ss * (1.0f / 512.0f) - mu * mu;
    float rs  = rsqrtf(var + 1e-5f);
    const float4* g4 = (const float4*)g;
    const float4* b4 = (const float4*)b;
    float4 G0 = g4[lane], G1 = g4[lane + 64];
    float4 B0 = b4[lane], B1 = b4[lane + 64];
    half4 h0, h1;
    h0[0] = (_Float16)((v0.x - mu) * rs * G0.x + B0.x);
    h0[1] = (_Float16)((v0.y - mu) * rs * G0.y + B0.y);
    h0[2] = (_Float16)((v0.z - mu) * rs * G0.z + B0.z);
    h0[3] = (_Float16)((v0.w - mu) * rs * G0.w + B0.w);
    h1[0] = (_Float16)((v1.x - mu) * rs * G1.x + B1.x);
    h1[1] = (_Float16)((v1.y - mu) * rs * G1.y + B1.y);
    h1[2] = (_Float16)((v1.z - mu) * rs * G1.z + B1.z);
    h1[3] = (_Float16)((v1.w - mu) * rs * G1.w + B1.w);
    half4* o = (half4*)(out + (size_t)row * N_EMBD);
    o[lane]      = h0;
    o[lane + 64] = h1;
}

// ---------------------------------------------------------------------------
// f16 MFMA GEMM: C[M][N] = A[M][K] @ Bt[N][K]^T
// + bijective chunked XCD swizzle (T1)
// + LDS chunk XOR-swizzle on frag reads (source-permuted, LDS dest linear)
// + LDS-staged coalesced epilogue (full-row vector stores)
// ---------------------------------------------------------------------------
template<int OUTF16, int RELU>
__global__ __launch_bounds__(256) void gemm_mfma(
    const _Float16* __restrict__ A, const _Float16* __restrict__ Bt,
    const float* __restrict__ bias, const float* __restrict__ resid,
    void* __restrict__ Cv, int M, int N, int K, int ldB)
{
    // 34816 B: K-loop uses first 16 KB (As|Bs); epilogue reuses whole block.
    __shared__ __attribute__((aligned(16))) _Float16 smem[128 * 136];
    _Float16* As = smem;
    _Float16* Bs = smem + 128 * 32;

    const int tid  = threadIdx.x;
    const int wid  = tid >> 6;
    const int lane = tid & 63;

    // chunked XCD swizzle (grids here always have nwg % 8 == 0)
    const int nx   = gridDim.x;
    const int nwg  = nx * gridDim.y;
    const int flat = blockIdx.y * nx + blockIdx.x;
    const int swzb = (flat & 7) * (nwg >> 3) + (flat >> 3);
    const int col0 = (swzb % nx) * 128;
    const int row0 = (swzb / nx) * 128;

    const int wr   = (wid >> 1) * 64;
    const int wc   = (wid & 1) * 64;

    const int sA    = wid * 2;
    const int lrow  = lane >> 2;
    const int lkswz = ((lane & 3) ^ ((lane >> 2) & 3) ^ (lane >> 4)) * 8;
    const _Float16* gA0 = A  + (size_t)(row0 + sA * 16 + lrow)       * K   + lkswz;
    const _Float16* gA1 = A  + (size_t)(row0 + (sA + 1) * 16 + lrow) * K   + lkswz;
    const _Float16* gB0 = Bt + (size_t)(col0 + sA * 16 + lrow)       * ldB + lkswz;
    const _Float16* gB1 = Bt + (size_t)(col0 + (sA + 1) * 16 + lrow) * ldB + lkswz;
    _Float16* lA0 = As + sA * 512;
    _Float16* lA1 = As + (sA + 1) * 512;
    _Float16* lB0 = Bs + sA * 512;
    _Float16* lB1 = Bs + (sA + 1) * 512;

    const int l15  = lane & 15;
    const int swzr = (l15 & 3) ^ ((l15 >> 2) & 3);
    const int gidx = ((lane >> 4) ^ swzr) * 8;
    const _Float16* fA = As + (size_t)(wr + l15) * 32 + gidx;
    const _Float16* fB = Bs + (size_t)(wc + l15) * 32 + gidx;

    f32x4 acc[4][4] = {};

    for (int k0 = 0; k0 < K; k0 += 32) {
        GLOAD_LDS16(gA0 + k0, lA0);
        GLOAD_LDS16(gA1 + k0, lA1);
        GLOAD_LDS16(gB0 + k0, lB0);
        GLOAD_LDS16(gB1 + k0, lB1);
        __syncthreads();
        half8 af[4], bf[4];
        #pragma unroll
        for (int m = 0; m < 4; ++m) af[m] = *(const half8*)(fA + m * 16 * 32);
        #pragma unroll
        for (int n = 0; n < 4; ++n) bf[n] = *(const half8*)(fB + n * 16 * 32);
        #pragma unroll
        for (int m = 0; m < 4; ++m)
            #pragma unroll
            for (int n = 0; n < 4; ++n)
                acc[m][n] = __builtin_amdgcn_mfma_f32_16x16x32_f16(
                    af[m], bf[n], acc[m][n], 0, 0, 0);
        __syncthreads();
    }

    // ---- epilogue: stage C tile in LDS, emit coalesced row stores ----
    if (OUTF16) {
        // full 128x128 f16 tile, row stride 136 halves (16B-aligned rows)
        #pragma unroll
        for (int m = 0; m < 4; ++m) {
            #pragma unroll
            for (int n = 0; n < 4; ++n) {
                #pragma unroll
                for (int r = 0; r < 4; ++r) {
                    int lr = wr + m * 16 + (lane >> 4) * 4 + r;
                    int lc = wc + n * 16 + l15;
                    float v = acc[m][n][r];
                    if (bias) v += bias[col0 + lc];
                    if (RELU) v = fmaxf(v, 0.f);
                    smem[lr * 136 + lc] = (_Float16)v;
                }
            }
        }
        __syncthreads();
        #pragma unroll
        for (int p = 0; p < 8; ++p) {
            int lr = p * 16 + (tid >> 4);
            int c8 = (tid & 15) * 8;
            *(half8*)((_Float16*)Cv + (size_t)(row0 + lr) * N + col0 + c8) =
                *(const half8*)&smem[lr * 136 + c8];
        }
    } else {
        // two col-half rounds of 128x64 f32, row stride 68 floats
        float* sf = (float*)smem;
        #pragma unroll
        for (int h = 0; h < 2; ++h) {
            __syncthreads();
            if ((wid & 1) == h) {
                #pragma unroll
                for (int m = 0; m < 4; ++m)
                    #pragma unroll
                    for (int n = 0; n < 4; ++n)
                        #pragma unroll
                        for (int r = 0; r < 4; ++r)
                            sf[(wr + m * 16 + (lane >> 4) * 4 + r) * 68 + n * 16 + l15]
                                = acc[m][n][r];
            }
            __syncthreads();
            #pragma unroll
            for (int p = 0; p < 8; ++p) {
                int lr = p * 16 + (tid >> 4);
                int cc = col0 + h * 64 + (tid & 15) * 4;
                float4 v4 = *(const float4*)&sf[lr * 68 + (tid & 15) * 4];
                if (bias) {
                    float4 b4 = *(const float4*)&bias[cc];
                    v4.x += b4.x; v4.y += b4.y; v4.z += b4.z; v4.w += b4.w;
                }
                if (resid) {
                    float4 r4 = *(const float4*)&resid[(size_t)(row0 + lr) * N + cc];
                    v4.x += r4.x; v4.y += r4.y; v4.z += r4.z; v4.w += r4.w;
                }
                *(float4*)((float*)Cv + (size_t)(row0 + lr) * N + cc) = v4;
            }
        }
    }
}

// ---------------------------------------------------------------------------
// MFMA flash-attention v2. One block per (batch, head, q-half of 128 rows);
// 4 waves x 32 q-rows. K staged [32][88]; V transposed [64][40] with
// conflict-free mapping; P via per-wave LDS [32][40].
// ---------------------------------------------------------------------------
template<int CAUSAL>
__global__ __launch_bounds__(256) void attn_mfma(
    const _Float16* __restrict__ Q, int ldq,
    const _Float16* __restrict__ Kg, const _Float16* __restrict__ Vg, int ldkv,
    const int* __restrict__ mask, const unsigned* __restrict__ flagp,
    _Float16* __restrict__ O)
{
    __shared__ __attribute__((aligned(16))) _Float16 Ks[32 * 88];
    __shared__ __attribute__((aligned(16))) _Float16 Vt[64 * 40];
    __shared__ __attribute__((aligned(16))) _Float16 Pl[4][32 * 40];

    const int qt   = blockIdx.x & 1;
    const int bh   = blockIdx.x >> 1;
    const int b    = bh >> 3;
    const int h    = bh & 7;
    const int tid  = threadIdx.x;
    const int wid  = tid >> 6;
    const int lane = tid & 63;
    const int l15  = lane & 15;
    const int kg8  = (lane >> 4) * 8;
    const int q0   = qt * 128 + wid * 32;
    const unsigned allones = flagp[0];
    const float scale = 0.04419417382415922f;   // 512^-0.5

    half8 af[2][2];
    #pragma unroll
    for (int m = 0; m < 2; ++m)
        #pragma unroll
        for (int c = 0; c < 2; ++c)
            af[m][c] = *(const half8*)(Q + (size_t)(b * TBLK + q0 + m * 16 + l15) * ldq
                                         + h * HEADD + c * 32 + kg8);

    f32x4 o[2][4] = {};
    float mrun[2][4], lrun[2][4];
    #pragma unroll
    for (int m = 0; m < 2; ++m)
        #pragma unroll
        for (int r = 0; r < 4; ++r) { mrun[m][r] = -1e30f; lrun[m][r] = 0.f; }

    _Float16* PlW = Pl[wid];
    const int kk = tid & 31;         // k row within tile
    const int dg = tid >> 5;         // 0..7 d-group of 8
    const _Float16* kgp = Kg + (size_t)(b * TBLK) * ldkv + h * HEADD;
    const _Float16* vgp = Vg + (size_t)(b * TBLK) * ldkv + h * HEADD;
    const int ktend = CAUSAL ? qt * 128 + 128 : TBLK;

    for (int kt = 0; kt < ktend; kt += 32) {
        __syncthreads();
        {
            half8 kv = *(const half8*)(kgp + (size_t)(kt + kk) * ldkv + dg * 8);
            half8 vv = *(const half8*)(vgp + (size_t)(kt + kk) * ldkv + dg * 8);
            *(half8*)&Ks[kk * 88 + dg * 8] = kv;
            #pragma unroll
            for (int j = 0; j < 8; ++j)
                Vt[(dg * 8 + j) * 40 + kk] = vv[j];
        }
        __syncthreads();
        if (!CAUSAL || kt < q0 + 32) {
            f32x4 s[2][2] = {};
            #pragma unroll
            for (int c = 0; c < 2; ++c) {
                half8 bk0 = *(const half8*)&Ks[(l15)      * 88 + c * 32 + kg8];
                half8 bk1 = *(const half8*)&Ks[(16 + l15) * 88 + c * 32 + kg8];
                #pragma unroll
                for (int m = 0; m < 2; ++m) {
                    s[m][0] = __builtin_amdgcn_mfma_f32_16x16x32_f16(af[m][c], bk0, s[m][0], 0, 0, 0);
                    s[m][1] = __builtin_amdgcn_mfma_f32_16x16x32_f16(af[m][c], bk1, s[m][1], 0, 0, 0);
                }
            }
            #pragma unroll
            for (int m = 0; m < 2; ++m) {
                #pragma unroll
                for (int r = 0; r < 4; ++r) {
                    float s0 = s[m][0][r] * scale;
                    float s1 = s[m][1][r] * scale;
                    const int qrow = q0 + m * 16 + (lane >> 4) * 4 + r;
                    if (!allones) {
                        const int* mr = mask + (size_t)(b * TBLK + qrow) * TBLK + kt;
                        if (mr[l15] == 0)      s0 = -1e9f;
                        if (mr[16 + l15] == 0) s1 = -1e9f;
                    }
                    if (CAUSAL) {
                        if (kt + l15 > qrow)      s0 = -1e9f;
                        if (kt + 16 + l15 > qrow) s1 = -1e9f;
                    }
                    float tm = fmaxf(s0, s1);
                    tm = fmaxf(tm, __shfl_xor(tm, 1));
                    tm = fmaxf(tm, __shfl_xor(tm, 2));
                    tm = fmaxf(tm, __shfl_xor(tm, 4));
                    tm = fmaxf(tm, __shfl_xor(tm, 8));
                    float mnew = fmaxf(mrun[m][r], tm);
                    float fr = __expf(mrun[m][r] - mnew);
                    float p0 = __expf(s0 - mnew);
                    float p1 = __expf(s1 - mnew);
                    float rs = p0 + p1;
                    rs += __shfl_xor(rs, 1);
                    rs += __shfl_xor(rs, 2);
                    rs += __shfl_xor(rs, 4);
                    rs += __shfl_xor(rs, 8);
                    lrun[m][r] = lrun[m][r] * fr + rs;
                    mrun[m][r] = mnew;
                    o[m][0][r] *= fr; o[m][1][r] *= fr;
                    o[m][2][r] *= fr; o[m][3][r] *= fr;
                    _Float16* pw = PlW + (m * 16 + (lane >> 4) * 4 + r) * 40;
                    pw[l15]      = (_Float16)p0;
                    pw[16 + l15] = (_Float16)p1;
                }
            }
            half8 pa[2];
            #pragma unroll
            for (int m = 0; m < 2; ++m)
                pa[m] = *(const half8*)&PlW[(m * 16 + l15) * 40 + kg8];
            #pragma unroll
            for (int dn = 0; dn < 4; ++dn) {
                half8 bv = *(const half8*)&Vt[(dn * 16 + l15) * 40 + kg8];
                #pragma unroll
                for (int m = 0; m < 2; ++m)
                    o[m][dn] = __builtin_amdgcn_mfma_f32_16x16x32_f16(pa[m], bv, o[m][dn], 0, 0, 0);
            }
        }
    }

    #pragma unroll
    for (int m = 0; m < 2; ++m) {
        #pragma unroll
        for (int r = 0; r < 4; ++r) {
            float inv = 1.0f / lrun[m][r];
            const int qrow = q0 + m * 16 + (lane >> 4) * 4 + r;
            _Float16* op = O + (size_t)(b * TBLK + qrow) * N_EMBD + h * HEADD;
            #pragma unroll
            for (int dn = 0; dn < 4; ++dn)
                op[dn * 16 + l15] = (_Float16)(o[m][dn][r] * inv);
        }
    }
}

// ---------------------------------------------------------------------------
extern "C" void kernel_launch(void* const* d_in, const int* in_sizes, int n_in,
                              void* d_out, int out_size, void* d_ws, size_t ws_size,
                              hipStream_t stream) {
    const float* x    = (const float*)d_in[0];
    const float* ca   = (const float*)d_in[1];
    const int*   x_m  = (const int*)d_in[2];
    const int*   ca_m = (const int*)d_in[3];
    const float* Wq_s = (const float*)d_in[4];
    const float* Wk_s = (const float*)d_in[5];
    const float* Wv_s = (const float*)d_in[6];
    const float* Wo_s = (const float*)d_in[7];
    const float* bo_s = (const float*)d_in[8];
    const float* Wq_c = (const float*)d_in[9];
    const float* Wk_c = (const float*)d_in[10];
    const float* Wv_c = (const float*)d_in[11];
    const float* Wo_c = (const float*)d_in[12];
    const float* bo_c = (const float*)d_in[13];
    const float* g1   = (const float*)d_in[14];
    const float* be1  = (const float*)d_in[15];
    const float* g2   = (const float*)d_in[16];
    const float* be2  = (const float*)d_in[17];
    const float* g3   = (const float*)d_in[18];
    const float* be3  = (const float*)d_in[19];
    const float* Wf1  = (const float*)d_in[20];
    const float* bf1  = (const float*)d_in[21];
    const float* Wf2  = (const float*)d_in[22];
    const float* bf2  = (const float*)d_in[23];

    float* out = (float*)d_out;
    char*  ws  = (char*)d_ws;

    const size_t MiB = 1024 * 1024;
    if (ws_size < 90 * MiB) return;

    _Float16* LNh  = (_Float16*)(ws);             // 16 MiB; also ATT out
    _Float16* QKV  = (_Float16*)(ws + 16 * MiB);  // [16384][1536] 48 MiB (16..64)
    _Float16* Qc   = (_Float16*)(ws + 16 * MiB);  // [16384][512]  (cross phase)
    _Float16* KVc  = (_Float16*)(ws + 32 * MiB);  // [16384][1024] (cross phase)
    _Float16* FFC  = (_Float16*)(ws + 16 * MiB);  // [16384][2048] 64 MiB (FF phase)
    _Float16* cah  = (_Float16*)(ws + 64 * MiB);  // 16 MiB
    _Float16* wqkv_s = (_Float16*)(ws + 80 * MiB);      // [1536][512]
    _Float16* wos    = wqkv_s + 1536 * 512;             // [512][512]
    _Float16* wqc    = wos    + 512 * 512;              // [512][512]
    _Float16* wkv_c  = wqc    + 512 * 512;              // [1024][512]
    _Float16* woc    = wkv_c  + 1024 * 512;             // [512][512]
    _Float16* wf1t   = woc    + 512 * 512;              // [2048][512]
    _Float16* wf2t   = wf1t   + 2048 * 512;             // [512][2048]
    unsigned* flags  = (unsigned*)(ws + 89 * MiB);      // [0]=x_m, [1]=ca_m

    dim3 blk(256);
    dim3 g5(16, 16);
    flag_init<<<1, 64, 0, stream>>>(flags);
    mask_check<<<1024, blk, 0, stream>>>(x_m,  MROWS * TBLK, flags);
    mask_check<<<1024, blk, 0, stream>>>(ca_m, MROWS * TBLK, flags + 1);

    wtrans<<<g5, blk, 0, stream>>>(Wq_s, wqkv_s,              N_EMBD, N_EMBD);
    wtrans<<<g5, blk, 0, stream>>>(Wk_s, wqkv_s + 512 * 512,  N_EMBD, N_EMBD);
    wtrans<<<g5, blk, 0, stream>>>(Wv_s, wqkv_s + 1024 * 512, N_EMBD, N_EMBD);
    wtrans<<<g5, blk, 0, stream>>>(Wo_s, wos, N_EMBD, N_EMBD);
    wtrans<<<g5, blk, 0, stream>>>(Wq_c, wqc, N_EMBD, N_EMBD);
    wtrans<<<g5, blk, 0, stream>>>(Wk_c, wkv_c,             N_EMBD, N_EMBD);
    wtrans<<<g5, blk, 0, stream>>>(Wv_c, wkv_c + 512 * 512, N_EMBD, N_EMBD);
    wtrans<<<g5, blk, 0, stream>>>(Wo_c, woc, N_EMBD, N_EMBD);
    wtrans<<<dim3(FF_DIM / 32, N_EMBD / 32), blk, 0, stream>>>(Wf1, wf1t, N_EMBD, FF_DIM);
    wtrans<<<dim3(N_EMBD / 32, FF_DIM / 32), blk, 0, stream>>>(Wf2, wf2t, FF_DIM, N_EMBD);
    conv_f16<<<2048, blk, 0, stream>>>(ca, cah, MROWS * N_EMBD / 4);

    dim3 gp(N_EMBD / 128, MROWS / 128);    // (4, 128)
    dim3 gqkv(1536 / 128, MROWS / 128);    // (12, 128)
    dim3 gkv(1024 / 128, MROWS / 128);     // (8, 128)
    dim3 gf1(FF_DIM / 128, MROWS / 128);   // (16, 128)
    dim3 ga(BATCH * NHEADS * 2);

    // --- self-attention: out = x + Attn(LN1(x)) @ Wo + bo ---
    ln_kernel<<<MROWS / 4, blk, 0, stream>>>(x, LNh, g1, be1);
    gemm_mfma<1,0><<<gqkv, blk, 0, stream>>>(LNh, wqkv_s, nullptr, nullptr, QKV, MROWS, 1536, N_EMBD, N_EMBD);
    attn_mfma<1><<<ga, blk, 0, stream>>>(QKV, 1536, QKV + 512, QKV + 1024, 1536, x_m, flags, LNh);
    gemm_mfma<0,0><<<gp, blk, 0, stream>>>(LNh, wos, bo_s, x, out, MROWS, N_EMBD, N_EMBD, N_EMBD);

    // --- cross-attention: out = out + Attn(LN2(out), ca) @ Wo + bo ---
    ln_kernel<<<MROWS / 4, blk, 0, stream>>>(out, LNh, g2, be2);
    gemm_mfma<1,0><<<gp, blk, 0, stream>>>(LNh, wqc, nullptr, nullptr, Qc, MROWS, N_EMBD, N_EMBD, N_EMBD);
    gemm_mfma<1,0><<<gkv, blk, 0, stream>>>(cah, wkv_c, nullptr, nullptr, KVc, MROWS, 1024, N_EMBD, N_EMBD);
    attn_mfma<0><<<ga, blk, 0, stream>>>(Qc, 512, KVc, KVc + 512, 1024, ca_m, flags + 1, LNh);
    gemm_mfma<0,0><<<gp, blk, 0, stream>>>(LNh, woc, bo_c, out, out, MROWS, N_EMBD, N_EMBD, N_EMBD);

    // --- FFN: out = out + relu(LN3(out)@Wf1+bf1)@Wf2+bf2 ---
    ln_kernel<<<MROWS / 4, blk, 0, stream>>>(out, LNh, g3, be3);
    gemm_mfma<1,1><<<gf1, blk, 0, stream>>>(LNh, wf1t, bf1, nullptr, FFC, MROWS, FF_DIM, N_EMBD, N_EMBD);
    gemm_mfma<0,0><<<gp, blk, 0, stream>>>(FFC, wf2t, bf2, out, out, MROWS, N_EMBD, FF_DIM, FF_DIM);
}